// Round 3
// baseline (588.905 us; speedup 1.0000x reference)
//
#include <hip/hip_runtime.h>
#include <math.h>

// DifferentiableRiskBudgeting: B=512, P=256. One block (256 thr) per batch.
// Thread (ti=tid>>2, tj=tid&3) owns rows 4ti..4ti+3 x cols 64tj..64tj+63.
//   Rows +0..2: fp32 VGPRs as <2 x float> pairs -> v_pk_fma_f32.
//   Row  +3: fp32 LDS slab, stride 272 + tj-stride 68 (conflict-free b128).
// R6: amdgpu_waves_per_eu(2,2) — LDS caps us at 2 blocks/CU anyway; full
// register budget for the 192-float resident sigma tile.
// One barrier per PGD iteration (wave-local w copies, double-buffered stage).
// R7 (FAILED, +4%): fixed-7 Newton rounds — paid 2 chains/round serially.
// R8 (WIN, -40%): warm-started safeguarded Newton + early exit at |f|<=4e-6.
//   Post-mortem: each eval round costs ~500 cyc (chain+readlane+scalar), so
//   round COUNT is everything.
// R9: (a) fuse the min/max bracket chains INTO the first eval — S,N,mn,mx
//   are 4 independent DPP trees issued together; exit-check consumes only f,
//   so the common-case projection is ONE chain latency (mn/mx results die
//   unread). Bracket init moved into the slow path. (b) Aitken extrapolation
//   of tau (uniform scalar, off critical path) — geometric tau drift makes
//   tau_pred accurate enough to first-eval-exit earlier in the tail.
//   (c) guarded amdgpu_num_vgpr(256) probe: if the 128-VGPR split was an
//   allocator cap, freeing it kills AGPR-shuffle bloat in the matvec.

#define PP    256
#define MAXW  0.1f
#define EPSF  1e-8f
#define NPGD  250
#define NPOW  20
#define NILLMAX 10
#define FTOL  4e-6f

#define R3S   272   // sigma row-3 slab stride (floats); 272 % 32 == 16
#define TJS   68    // tj stride inside slab row;        68 % 32 == 4
#define WRDS  72    // w-copy block stride (64 data + 8 stagger)
#define VCOPY 280   // per-wave w copy stride

typedef float v2 __attribute__((ext_vector_type(2)));
typedef float v4t __attribute__((ext_vector_type(4)));

template<int CTRL>
__device__ __forceinline__ float dpp_zero(float x) {
    return __int_as_float(__builtin_amdgcn_update_dpp(
        0, __float_as_int(x), CTRL, 0xF, 0xF, true));
}
template<int CTRL>
__device__ __forceinline__ float dpp_keep(float x) {
    int xi = __float_as_int(x);
    return __int_as_float(__builtin_amdgcn_update_dpp(xi, xi, CTRL, 0xF, 0xF, false));
}
__device__ __forceinline__ float rdlane63(float x) {
    return __int_as_float(__builtin_amdgcn_readlane(__float_as_int(x), 63));
}
__device__ __forceinline__ float wave_sum63(float s) {
    s += dpp_zero<0x111>(s);
    s += dpp_zero<0x112>(s);
    s += dpp_zero<0x114>(s);
    s += dpp_zero<0x118>(s);
    s += dpp_zero<0x142>(s);
    s += dpp_zero<0x143>(s);
    return s;
}
__device__ __forceinline__ float wave_min63(float m) {
    m = fminf(m, dpp_keep<0x111>(m));
    m = fminf(m, dpp_keep<0x112>(m));
    m = fminf(m, dpp_keep<0x114>(m));
    m = fminf(m, dpp_keep<0x118>(m));
    m = fminf(m, dpp_keep<0x142>(m));
    m = fminf(m, dpp_keep<0x143>(m));
    return m;
}
__device__ __forceinline__ float wave_max63(float m) {
    m = fmaxf(m, dpp_keep<0x111>(m));
    m = fmaxf(m, dpp_keep<0x112>(m));
    m = fmaxf(m, dpp_keep<0x114>(m));
    m = fmaxf(m, dpp_keep<0x118>(m));
    m = fmaxf(m, dpp_keep<0x142>(m));
    m = fmaxf(m, dpp_keep<0x143>(m));
    return m;
}

__global__ __launch_bounds__(256)
__attribute__((amdgpu_waves_per_eu(2, 2)))
#if __has_attribute(amdgpu_num_vgpr)
__attribute__((amdgpu_num_vgpr(256)))
#endif
void drb_kernel(const float* __restrict__ sigma,
                const float* __restrict__ beta,
                const float* __restrict__ wprev,
                const float* __restrict__ pl1,
                const float* __restrict__ pl2,
                float* __restrict__ out)
{
    const int b    = blockIdx.x;
    const int tid  = threadIdx.x;
    const int lane = tid & 63;
    const int wv   = tid >> 6;
    const int ti   = tid >> 2;   // 0..63
    const int tj   = tid & 3;    // 0..3

    __shared__ __align__(16) float sigR3[64 * R3S];   // 69632 B
    __shared__ __align__(16) float wcop[4 * VCOPY];   //  4480 B
    __shared__ __align__(16) float stage[2][256];     //  2048 B

    const float* Sb = sigma + (size_t)b * (PP * PP);

    // ---- stage sigma: rows +0..2 -> v2 VGPR pairs; row +3 -> LDS slab
    v2 s0[32], s1[32], s2[32];
    {
        const float* r0 = Sb + (4 * ti + 0) * PP + 64 * tj;
        const float* r1 = Sb + (4 * ti + 1) * PP + 64 * tj;
        const float* r2 = Sb + (4 * ti + 2) * PP + 64 * tj;
#pragma unroll
        for (int k = 0; k < 16; ++k) {
            v4t t0 = *(const v4t*)(r0 + 4 * k);
            v4t t1 = *(const v4t*)(r1 + 4 * k);
            v4t t2 = *(const v4t*)(r2 + 4 * k);
            s0[2*k]   = __builtin_shufflevector(t0, t0, 0, 1);
            s0[2*k+1] = __builtin_shufflevector(t0, t0, 2, 3);
            s1[2*k]   = __builtin_shufflevector(t1, t1, 0, 1);
            s1[2*k+1] = __builtin_shufflevector(t1, t1, 2, 3);
            s2[2*k]   = __builtin_shufflevector(t2, t2, 0, 1);
            s2[2*k+1] = __builtin_shufflevector(t2, t2, 2, 3);
        }
        const float* r3 = Sb + (4 * ti + 3) * PP + 64 * tj;
        float* d3 = sigR3 + ti * R3S + TJS * tj;
#pragma unroll
        for (int k = 0; k < 16; ++k)
            *(v4t*)(d3 + 4 * k) = *(const v4t*)(r3 + 4 * k);
        // row-3 slab is written and read by the SAME thread -> no barrier.
    }

    const float bt   = beta[b * PP + tid];
    const float wp   = wprev[b * PP + tid];
    const float lam1 = expf(pl1[0]);
    const float lam2 = expf(pl2[0]);

    float* wme = wcop + wv * VCOPY;                // my wave's full-vector copy
    const int wst = 4 * lane + 8 * (lane >> 4);    // staggered write slot
    const float* wrd = wme + WRDS * tj;            // matvec read base (72*tj)

    // y = Sigma * w (w from my wave's copy); returns y[row tid]
    auto matvec = [&]() -> float {
        v2 y0 = {0.f, 0.f}, y1 = {0.f, 0.f}, y2 = {0.f, 0.f}, y3 = {0.f, 0.f};
        const float* p3 = sigR3 + ti * R3S + TJS * tj;
#pragma unroll
        for (int k = 0; k < 16; ++k) {
            v4t wq = *(const v4t*)(wrd + 4 * k);
            v2 w01 = __builtin_shufflevector(wq, wq, 0, 1);
            v2 w23 = __builtin_shufflevector(wq, wq, 2, 3);
            y0 = __builtin_elementwise_fma(s0[2*k],   w01, y0);
            y0 = __builtin_elementwise_fma(s0[2*k+1], w23, y0);
            y1 = __builtin_elementwise_fma(s1[2*k],   w01, y1);
            y1 = __builtin_elementwise_fma(s1[2*k+1], w23, y1);
            y2 = __builtin_elementwise_fma(s2[2*k],   w01, y2);
            y2 = __builtin_elementwise_fma(s2[2*k+1], w23, y2);
            v4t q = *(const v4t*)(p3 + 4 * k);
            v2 q01 = __builtin_shufflevector(q, q, 0, 1);
            v2 q23 = __builtin_shufflevector(q, q, 2, 3);
            y3 = __builtin_elementwise_fma(q01, w01, y3);
            y3 = __builtin_elementwise_fma(q23, w23, y3);
        }
        float r0 = y0.x + y0.y, r1 = y1.x + y1.y;
        float r2 = y2.x + y2.y, r3 = y3.x + y3.y;
        r0 += dpp_zero<0x4E>(r0); r1 += dpp_zero<0x4E>(r1);
        r2 += dpp_zero<0x4E>(r2); r3 += dpp_zero<0x4E>(r3);
        r0 += dpp_zero<0xB1>(r0); r1 += dpp_zero<0xB1>(r1);
        r2 += dpp_zero<0xB1>(r2); r3 += dpp_zero<0xB1>(r3);
        float a01 = (tj & 1) ? r1 : r0;
        float a23 = (tj & 1) ? r3 : r2;
        return (tj & 2) ? a23 : a01;
    };

    // ---- power iteration: each wave's copy initialized to 1/16 (wave-local)
    {
        v4t c = {0.0625f, 0.0625f, 0.0625f, 0.0625f};
        *(v4t*)(wme + wst) = c;
    }

    float y_last = 0.f, a_last = 1.f;
#pragma unroll 1
    for (int pi = 0; pi < NPOW; ++pi) {
        float y = matvec();
        stage[pi & 1][tid] = y;
        __syncthreads();
        v4t u4 = *(const v4t*)(&stage[pi & 1][4 * lane]);
        float ss = fmaf(u4.x, u4.x, fmaf(u4.y, u4.y, fmaf(u4.z, u4.z, u4.w * u4.w)));
        float a  = 1.f / (sqrtf(rdlane63(wave_sum63(ss))) + EPSF);
        v4t n4 = {a * u4.x, a * u4.y, a * u4.z, a * u4.w};
        *(v4t*)(wme + wst) = n4;          // full normalized vector, my copy
        y_last = y; a_last = a;
    }

    // ---- lmax = v' S v ; step
    float stepf;
    {
        float ysv = matvec();
        float p   = (a_last * y_last) * ysv;
        stage[0][tid] = p;
        __syncthreads();
        v4t p4 = *(const v4t*)(&stage[0][4 * lane]);
        float lmax = rdlane63(wave_sum63((p4.x + p4.y) + (p4.z + p4.w)));
        stepf = 1.f / (2.f * lmax + 2.f * lam2 + 1e-6f);
        __syncthreads();   // everyone done with stage[0] before PGD reuses it
    }

    // ---- PGD init: w0 = 1/256 (wave-local full copy)
    float w_own = 1.f / 256.f;
    {
        v4t c = {1.f/256.f, 1.f/256.f, 1.f/256.f, 1.f/256.f};
        *(v4t*)(wme + wst) = c;
    }
    const float Ac = 1.f - 2.f * lam2 * stepf;
    const float Bc = -2.f * stepf;
    const float Cc = stepf * (bt - lam1 + 2.f * lam2 * wp);

    float tau_pred = 0.f;   // warm-start/extrapolated probe for next iter
    float tau_last = 0.f;   // tau of previous iteration
    float dtau_last = 0.f;  // previous tau delta (for Aitken)

#pragma unroll 1
    for (int it = 0; it < NPGD; ++it) {
        float y = matvec();
        float v_own = fmaf(w_own, Ac, fmaf(y, Bc, Cc));
        const int sb = it & 1;
        stage[sb][tid] = v_own;
        __syncthreads();                      // the ONLY barrier this iteration

        v4t v4 = *(const v4t*)(&stage[sb][4 * lane]);

        // ---- fused eval#1 + bracket chains: S, N, mn, mx are 4 independent
        // DPP trees; the exit check consumes only f, so in the common case
        // the projection costs a single chain latency.
        float tau = tau_pred;
        float d0 = v4.x - tau, d1 = v4.y - tau;
        float d2 = v4.z - tau, d3 = v4.w - tau;
        float c0 = __builtin_amdgcn_fmed3f(d0, 0.f, MAXW);
        float c1 = __builtin_amdgcn_fmed3f(d1, 0.f, MAXW);
        float c2 = __builtin_amdgcn_fmed3f(d2, 0.f, MAXW);
        float c3 = __builtin_amdgcn_fmed3f(d3, 0.f, MAXW);
        float n0 = ((d0 > 0.f) & (d0 < MAXW)) ? 1.f : 0.f;
        float n1 = ((d1 > 0.f) & (d1 < MAXW)) ? 1.f : 0.f;
        float n2 = ((d2 > 0.f) & (d2 < MAXW)) ? 1.f : 0.f;
        float n3 = ((d3 > 0.f) & (d3 < MAXW)) ? 1.f : 0.f;
        float mnl = fminf(fminf(v4.x, v4.y), fminf(v4.z, v4.w));
        float mxl = fmaxf(fmaxf(v4.x, v4.y), fmaxf(v4.z, v4.w));
        float Sw  = wave_sum63((c0 + c1) + (c2 + c3));
        float Nw  = wave_sum63((n0 + n1) + (n2 + n3));
        float mnw = wave_min63(mnl);
        float mxw = wave_max63(mxl);
        float f   = rdlane63(Sw) - 1.f;
        float cnt = rdlane63(Nw);

        if (!(fabsf(f) <= FTOL)) {            // uniform scalar branch
            float mn = rdlane63(mnw);
            float mx = rdlane63(mxw);
            // Bracket init from known values:
            //   f(mn-MAXW)=256*MAXW-1 (>0),  f(mx)=-1 (<0), plus eval#1.
            bool pos0 = f > 0.f;
            float lo  = pos0 ? tau : mn - MAXW;
            float flo = pos0 ? f   : 256.f * MAXW - 1.f;
            float hi  = pos0 ? mx  : tau;
            float fhi = pos0 ? -1.f : f;
            int side  = pos0 ? 1 : -1;
#pragma unroll 1
            for (int r = 1; r < NILLMAX; ++r) {
                // Newton (exact on the current linear segment); Illinois
                // secant fallback when out-of-bracket / cnt==0 / NaN.
                float tn = fmaf(f, __builtin_amdgcn_rcpf(cnt), tau);
                float ts = (lo * fhi - hi * flo) * __builtin_amdgcn_rcpf(fhi - flo);
                bool good = (tn > lo) & (tn < hi);
                tau = good ? tn : ts;
                float e0 = v4.x - tau, e1 = v4.y - tau;
                float e2 = v4.z - tau, e3 = v4.w - tau;
                float g0 = __builtin_amdgcn_fmed3f(e0, 0.f, MAXW);
                float g1 = __builtin_amdgcn_fmed3f(e1, 0.f, MAXW);
                float g2 = __builtin_amdgcn_fmed3f(e2, 0.f, MAXW);
                float g3 = __builtin_amdgcn_fmed3f(e3, 0.f, MAXW);
                float m0 = ((e0 > 0.f) & (e0 < MAXW)) ? 1.f : 0.f;
                float m1 = ((e1 > 0.f) & (e1 < MAXW)) ? 1.f : 0.f;
                float m2 = ((e2 > 0.f) & (e2 < MAXW)) ? 1.f : 0.f;
                float m3 = ((e3 > 0.f) & (e3 < MAXW)) ? 1.f : 0.f;
                float Sr = wave_sum63((g0 + g1) + (g2 + g3));
                float Nr = wave_sum63((m0 + m1) + (m2 + m3));
                f   = rdlane63(Sr) - 1.f;
                cnt = rdlane63(Nr);
                if (fabsf(f) <= FTOL) break;  // uniform
                bool pos = f > 0.f;
                float nflo = pos ? f   : ((side < 0) ? 0.5f * flo : flo);
                float nfhi = pos ? ((side > 0) ? 0.5f * fhi : fhi) : f;
                lo  = pos ? tau : lo;
                hi  = pos ? hi  : tau;
                flo = nflo; fhi = nfhi;
                side = pos ? 1 : -1;
            }
        }

        // ---- Aitken predictor (uniform, off critical path): tau drifts
        // geometrically near the PGD fixed point; extrapolate the limit.
        {
            float dtau = tau - tau_last;
            float rho  = dtau * __builtin_amdgcn_rcpf(dtau_last);
            bool okx = (fabsf(dtau_last) > 1e-20f) & (rho > 0.f) &
                       (rho < 0.9f) & (fabsf(dtau) < 1e-2f);
            float extr = okx ? dtau * rho * __builtin_amdgcn_rcpf(1.f - rho) : 0.f;
            tau_pred = tau + extr;
            tau_last = tau;
            dtau_last = dtau;
        }

        v4t w4 = {__builtin_amdgcn_fmed3f(v4.x - tau, 0.f, MAXW),
                  __builtin_amdgcn_fmed3f(v4.y - tau, 0.f, MAXW),
                  __builtin_amdgcn_fmed3f(v4.z - tau, 0.f, MAXW),
                  __builtin_amdgcn_fmed3f(v4.w - tau, 0.f, MAXW)};
        *(v4t*)(wme + wst) = w4;              // full projected w, my wave's copy
        w_own = __builtin_amdgcn_fmed3f(v_own - tau, 0.f, MAXW);
    }

    // ---- renormalize + store
    stage[0][tid] = w_own;
    __syncthreads();
    v4t w4 = *(const v4t*)(&stage[0][4 * lane]);
    float S = rdlane63(wave_sum63((w4.x + w4.y) + (w4.z + w4.w)));
    out[b * PP + tid] = w_own / (S + EPSF);
}

extern "C" void kernel_launch(void* const* d_in, const int* in_sizes, int n_in,
                              void* d_out, int out_size, void* d_ws, size_t ws_size,
                              hipStream_t stream) {
    const float* sigma  = (const float*)d_in[0];
    const float* beta   = (const float*)d_in[1];
    const float* wprevp = (const float*)d_in[2];
    const float* pl1    = (const float*)d_in[3];
    const float* pl2    = (const float*)d_in[4];
    float* outp = (float*)d_out;
    drb_kernel<<<dim3(512), dim3(256), 0, stream>>>(sigma, beta, wprevp, pl1, pl2, outp);
}

// Round 4
// 556.003 us; speedup vs baseline: 1.0592x; 1.0592x over previous
//
#include <hip/hip_runtime.h>
#include <math.h>

// DifferentiableRiskBudgeting: B=512, P=256. One block (256 thr) per batch.
// Thread (ti=tid>>2, tj=tid&3) owns rows 4ti..4ti+3 x cols 64tj..64tj+63.
//   Rows +0..2: fp32 VGPRs as <2 x float> pairs -> v_pk_fma_f32.
//   Row  +3: fp32 LDS slab, stride 272 + tj-stride 68 (conflict-free b128).
// R6: amdgpu_waves_per_eu(2,2); LDS caps at 2 blocks/CU.
// R7 (FAILED, +4%): fixed-7 Newton rounds — paid 2 chains/round serially.
// R8 (WIN, -40%): warm-started safeguarded Newton + early exit at |f|<=4e-6.
//   Each eval round costs ~500 cyc wall; round COUNT is everything.
// R9 (NEUTRAL): fused mn/mx/N into eval#1 + Aitken — fast-path exit rate was
//   already ~1, fusion latency-hidden, VGPR_Count stayed 128.
// R10: (a) amdgpu_agpr_alloc(0) [guarded]: VGPR_Count=128 all session means
//   sigma is split into the AGPR half; static VALU ~230/iter vs ~600
//   effective implies ~2.6x inflation = v_accvgpr_read per pk_fma operand.
//   Zero AGPRs => all 256 regs arch => moves die. Demand ~230 < 256, no
//   spill expected; occupancy unchanged (8 waves/CU).
//   (b) lean fast path: S-chain only (18 VALU); N/mn/mx trees recomputed in
//   the (rare) slow path. Saves ~34 always-paid issue slots per iter.

#define PP    256
#define MAXW  0.1f
#define EPSF  1e-8f
#define NPGD  250
#define NPOW  20
#define NILLMAX 10
#define FTOL  4e-6f

#define R3S   272   // sigma row-3 slab stride (floats); 272 % 32 == 16
#define TJS   68    // tj stride inside slab row;        68 % 32 == 4
#define WRDS  72    // w-copy block stride (64 data + 8 stagger)
#define VCOPY 280   // per-wave w copy stride

typedef float v2 __attribute__((ext_vector_type(2)));
typedef float v4t __attribute__((ext_vector_type(4)));

template<int CTRL>
__device__ __forceinline__ float dpp_zero(float x) {
    return __int_as_float(__builtin_amdgcn_update_dpp(
        0, __float_as_int(x), CTRL, 0xF, 0xF, true));
}
template<int CTRL>
__device__ __forceinline__ float dpp_keep(float x) {
    int xi = __float_as_int(x);
    return __int_as_float(__builtin_amdgcn_update_dpp(xi, xi, CTRL, 0xF, 0xF, false));
}
__device__ __forceinline__ float rdlane63(float x) {
    return __int_as_float(__builtin_amdgcn_readlane(__float_as_int(x), 63));
}
__device__ __forceinline__ float wave_sum63(float s) {
    s += dpp_zero<0x111>(s);
    s += dpp_zero<0x112>(s);
    s += dpp_zero<0x114>(s);
    s += dpp_zero<0x118>(s);
    s += dpp_zero<0x142>(s);
    s += dpp_zero<0x143>(s);
    return s;
}
__device__ __forceinline__ float wave_min63(float m) {
    m = fminf(m, dpp_keep<0x111>(m));
    m = fminf(m, dpp_keep<0x112>(m));
    m = fminf(m, dpp_keep<0x114>(m));
    m = fminf(m, dpp_keep<0x118>(m));
    m = fminf(m, dpp_keep<0x142>(m));
    m = fminf(m, dpp_keep<0x143>(m));
    return m;
}
__device__ __forceinline__ float wave_max63(float m) {
    m = fmaxf(m, dpp_keep<0x111>(m));
    m = fmaxf(m, dpp_keep<0x112>(m));
    m = fmaxf(m, dpp_keep<0x114>(m));
    m = fmaxf(m, dpp_keep<0x118>(m));
    m = fmaxf(m, dpp_keep<0x142>(m));
    m = fmaxf(m, dpp_keep<0x143>(m));
    return m;
}

__global__ __launch_bounds__(256)
__attribute__((amdgpu_waves_per_eu(2, 2)))
#if __has_attribute(amdgpu_num_vgpr)
__attribute__((amdgpu_num_vgpr(256)))
#endif
#if __has_attribute(amdgpu_agpr_alloc)
__attribute__((amdgpu_agpr_alloc(0)))
#endif
void drb_kernel(const float* __restrict__ sigma,
                const float* __restrict__ beta,
                const float* __restrict__ wprev,
                const float* __restrict__ pl1,
                const float* __restrict__ pl2,
                float* __restrict__ out)
{
    const int b    = blockIdx.x;
    const int tid  = threadIdx.x;
    const int lane = tid & 63;
    const int wv   = tid >> 6;
    const int ti   = tid >> 2;   // 0..63
    const int tj   = tid & 3;    // 0..3

    __shared__ __align__(16) float sigR3[64 * R3S];   // 69632 B
    __shared__ __align__(16) float wcop[4 * VCOPY];   //  4480 B
    __shared__ __align__(16) float stage[2][256];     //  2048 B

    const float* Sb = sigma + (size_t)b * (PP * PP);

    // ---- stage sigma: rows +0..2 -> v2 VGPR pairs; row +3 -> LDS slab
    v2 s0[32], s1[32], s2[32];
    {
        const float* r0 = Sb + (4 * ti + 0) * PP + 64 * tj;
        const float* r1 = Sb + (4 * ti + 1) * PP + 64 * tj;
        const float* r2 = Sb + (4 * ti + 2) * PP + 64 * tj;
#pragma unroll
        for (int k = 0; k < 16; ++k) {
            v4t t0 = *(const v4t*)(r0 + 4 * k);
            v4t t1 = *(const v4t*)(r1 + 4 * k);
            v4t t2 = *(const v4t*)(r2 + 4 * k);
            s0[2*k]   = __builtin_shufflevector(t0, t0, 0, 1);
            s0[2*k+1] = __builtin_shufflevector(t0, t0, 2, 3);
            s1[2*k]   = __builtin_shufflevector(t1, t1, 0, 1);
            s1[2*k+1] = __builtin_shufflevector(t1, t1, 2, 3);
            s2[2*k]   = __builtin_shufflevector(t2, t2, 0, 1);
            s2[2*k+1] = __builtin_shufflevector(t2, t2, 2, 3);
        }
        const float* r3 = Sb + (4 * ti + 3) * PP + 64 * tj;
        float* d3 = sigR3 + ti * R3S + TJS * tj;
#pragma unroll
        for (int k = 0; k < 16; ++k)
            *(v4t*)(d3 + 4 * k) = *(const v4t*)(r3 + 4 * k);
        // row-3 slab is written and read by the SAME thread -> no barrier.
    }

    const float bt   = beta[b * PP + tid];
    const float wp   = wprev[b * PP + tid];
    const float lam1 = expf(pl1[0]);
    const float lam2 = expf(pl2[0]);

    float* wme = wcop + wv * VCOPY;                // my wave's full-vector copy
    const int wst = 4 * lane + 8 * (lane >> 4);    // staggered write slot
    const float* wrd = wme + WRDS * tj;            // matvec read base (72*tj)

    // y = Sigma * w (w from my wave's copy); returns y[row tid]
    auto matvec = [&]() -> float {
        v2 y0 = {0.f, 0.f}, y1 = {0.f, 0.f}, y2 = {0.f, 0.f}, y3 = {0.f, 0.f};
        const float* p3 = sigR3 + ti * R3S + TJS * tj;
#pragma unroll
        for (int k = 0; k < 16; ++k) {
            v4t wq = *(const v4t*)(wrd + 4 * k);
            v2 w01 = __builtin_shufflevector(wq, wq, 0, 1);
            v2 w23 = __builtin_shufflevector(wq, wq, 2, 3);
            y0 = __builtin_elementwise_fma(s0[2*k],   w01, y0);
            y0 = __builtin_elementwise_fma(s0[2*k+1], w23, y0);
            y1 = __builtin_elementwise_fma(s1[2*k],   w01, y1);
            y1 = __builtin_elementwise_fma(s1[2*k+1], w23, y1);
            y2 = __builtin_elementwise_fma(s2[2*k],   w01, y2);
            y2 = __builtin_elementwise_fma(s2[2*k+1], w23, y2);
            v4t q = *(const v4t*)(p3 + 4 * k);
            v2 q01 = __builtin_shufflevector(q, q, 0, 1);
            v2 q23 = __builtin_shufflevector(q, q, 2, 3);
            y3 = __builtin_elementwise_fma(q01, w01, y3);
            y3 = __builtin_elementwise_fma(q23, w23, y3);
        }
        float r0 = y0.x + y0.y, r1 = y1.x + y1.y;
        float r2 = y2.x + y2.y, r3 = y3.x + y3.y;
        r0 += dpp_zero<0x4E>(r0); r1 += dpp_zero<0x4E>(r1);
        r2 += dpp_zero<0x4E>(r2); r3 += dpp_zero<0x4E>(r3);
        r0 += dpp_zero<0xB1>(r0); r1 += dpp_zero<0xB1>(r1);
        r2 += dpp_zero<0xB1>(r2); r3 += dpp_zero<0xB1>(r3);
        float a01 = (tj & 1) ? r1 : r0;
        float a23 = (tj & 1) ? r3 : r2;
        return (tj & 2) ? a23 : a01;
    };

    // ---- power iteration: each wave's copy initialized to 1/16 (wave-local)
    {
        v4t c = {0.0625f, 0.0625f, 0.0625f, 0.0625f};
        *(v4t*)(wme + wst) = c;
    }

    float y_last = 0.f, a_last = 1.f;
#pragma unroll 1
    for (int pi = 0; pi < NPOW; ++pi) {
        float y = matvec();
        stage[pi & 1][tid] = y;
        __syncthreads();
        v4t u4 = *(const v4t*)(&stage[pi & 1][4 * lane]);
        float ss = fmaf(u4.x, u4.x, fmaf(u4.y, u4.y, fmaf(u4.z, u4.z, u4.w * u4.w)));
        float a  = 1.f / (sqrtf(rdlane63(wave_sum63(ss))) + EPSF);
        v4t n4 = {a * u4.x, a * u4.y, a * u4.z, a * u4.w};
        *(v4t*)(wme + wst) = n4;          // full normalized vector, my copy
        y_last = y; a_last = a;
    }

    // ---- lmax = v' S v ; step
    float stepf;
    {
        float ysv = matvec();
        float p   = (a_last * y_last) * ysv;
        stage[0][tid] = p;
        __syncthreads();
        v4t p4 = *(const v4t*)(&stage[0][4 * lane]);
        float lmax = rdlane63(wave_sum63((p4.x + p4.y) + (p4.z + p4.w)));
        stepf = 1.f / (2.f * lmax + 2.f * lam2 + 1e-6f);
        __syncthreads();   // everyone done with stage[0] before PGD reuses it
    }

    // ---- PGD init: w0 = 1/256 (wave-local full copy)
    float w_own = 1.f / 256.f;
    {
        v4t c = {1.f/256.f, 1.f/256.f, 1.f/256.f, 1.f/256.f};
        *(v4t*)(wme + wst) = c;
    }
    const float Ac = 1.f - 2.f * lam2 * stepf;
    const float Bc = -2.f * stepf;
    const float Cc = stepf * (bt - lam1 + 2.f * lam2 * wp);

    float tau_pred = 0.f;   // warm-start/extrapolated probe for next iter
    float tau_last = 0.f;   // tau of previous iteration
    float dtau_last = 0.f;  // previous tau delta (for Aitken)

#pragma unroll 1
    for (int it = 0; it < NPGD; ++it) {
        float y = matvec();
        float v_own = fmaf(w_own, Ac, fmaf(y, Bc, Cc));
        const int sb = it & 1;
        stage[sb][tid] = v_own;
        __syncthreads();                      // the ONLY barrier this iteration

        v4t v4 = *(const v4t*)(&stage[sb][4 * lane]);

        // ---- FAST PATH: evaluate only f(tau_pred) — a single S-chain.
        // N-count, min and max trees are deferred to the slow path.
        float tau = tau_pred;
        {
            float d0 = v4.x - tau, d1 = v4.y - tau;
            float d2 = v4.z - tau, d3 = v4.w - tau;
            float c0 = __builtin_amdgcn_fmed3f(d0, 0.f, MAXW);
            float c1 = __builtin_amdgcn_fmed3f(d1, 0.f, MAXW);
            float c2 = __builtin_amdgcn_fmed3f(d2, 0.f, MAXW);
            float c3 = __builtin_amdgcn_fmed3f(d3, 0.f, MAXW);
            float Sw = wave_sum63((c0 + c1) + (c2 + c3));
            float f  = rdlane63(Sw) - 1.f;

            if (!(fabsf(f) <= FTOL)) {        // uniform scalar branch
                // ---- SLOW PATH: build bracket (mn/mx) + count at tau.
                float mnl = fminf(fminf(v4.x, v4.y), fminf(v4.z, v4.w));
                float mxl = fmaxf(fmaxf(v4.x, v4.y), fmaxf(v4.z, v4.w));
                float n0 = ((d0 > 0.f) & (d0 < MAXW)) ? 1.f : 0.f;
                float n1 = ((d1 > 0.f) & (d1 < MAXW)) ? 1.f : 0.f;
                float n2 = ((d2 > 0.f) & (d2 < MAXW)) ? 1.f : 0.f;
                float n3 = ((d3 > 0.f) & (d3 < MAXW)) ? 1.f : 0.f;
                float mnw = wave_min63(mnl);
                float mxw = wave_max63(mxl);
                float Nw  = wave_sum63((n0 + n1) + (n2 + n3));
                float mn  = rdlane63(mnw);
                float mx  = rdlane63(mxw);
                float cnt = rdlane63(Nw);
                // Bracket init from known values:
                //   f(mn-MAXW)=256*MAXW-1 (>0),  f(mx)=-1 (<0), plus eval#1.
                bool pos0 = f > 0.f;
                float lo  = pos0 ? tau : mn - MAXW;
                float flo = pos0 ? f   : 256.f * MAXW - 1.f;
                float hi  = pos0 ? mx  : tau;
                float fhi = pos0 ? -1.f : f;
                int side  = pos0 ? 1 : -1;
#pragma unroll 1
                for (int r = 1; r < NILLMAX; ++r) {
                    // Newton (exact on current linear segment); Illinois
                    // secant fallback when out-of-bracket / cnt==0 / NaN.
                    float tn = fmaf(f, __builtin_amdgcn_rcpf(cnt), tau);
                    float ts = (lo * fhi - hi * flo) *
                               __builtin_amdgcn_rcpf(fhi - flo);
                    bool good = (tn > lo) & (tn < hi);
                    tau = good ? tn : ts;
                    float e0 = v4.x - tau, e1 = v4.y - tau;
                    float e2 = v4.z - tau, e3 = v4.w - tau;
                    float g0 = __builtin_amdgcn_fmed3f(e0, 0.f, MAXW);
                    float g1 = __builtin_amdgcn_fmed3f(e1, 0.f, MAXW);
                    float g2 = __builtin_amdgcn_fmed3f(e2, 0.f, MAXW);
                    float g3 = __builtin_amdgcn_fmed3f(e3, 0.f, MAXW);
                    float m0 = ((e0 > 0.f) & (e0 < MAXW)) ? 1.f : 0.f;
                    float m1 = ((e1 > 0.f) & (e1 < MAXW)) ? 1.f : 0.f;
                    float m2 = ((e2 > 0.f) & (e2 < MAXW)) ? 1.f : 0.f;
                    float m3 = ((e3 > 0.f) & (e3 < MAXW)) ? 1.f : 0.f;
                    float Sr = wave_sum63((g0 + g1) + (g2 + g3));
                    float Nr = wave_sum63((m0 + m1) + (m2 + m3));
                    f   = rdlane63(Sr) - 1.f;
                    cnt = rdlane63(Nr);
                    if (fabsf(f) <= FTOL) break;  // uniform
                    bool pos = f > 0.f;
                    float nflo = pos ? f   : ((side < 0) ? 0.5f * flo : flo);
                    float nfhi = pos ? ((side > 0) ? 0.5f * fhi : fhi) : f;
                    lo  = pos ? tau : lo;
                    hi  = pos ? hi  : tau;
                    flo = nflo; fhi = nfhi;
                    side = pos ? 1 : -1;
                }
            }
        }

        // ---- Aitken predictor (uniform, off critical path): tau drifts
        // geometrically near the PGD fixed point; extrapolate the limit.
        {
            float dtau = tau - tau_last;
            float rho  = dtau * __builtin_amdgcn_rcpf(dtau_last);
            bool okx = (fabsf(dtau_last) > 1e-20f) & (rho > 0.f) &
                       (rho < 0.9f) & (fabsf(dtau) < 1e-2f);
            float extr = okx ? dtau * rho * __builtin_amdgcn_rcpf(1.f - rho) : 0.f;
            tau_pred = tau + extr;
            tau_last = tau;
            dtau_last = dtau;
        }

        v4t w4 = {__builtin_amdgcn_fmed3f(v4.x - tau, 0.f, MAXW),
                  __builtin_amdgcn_fmed3f(v4.y - tau, 0.f, MAXW),
                  __builtin_amdgcn_fmed3f(v4.z - tau, 0.f, MAXW),
                  __builtin_amdgcn_fmed3f(v4.w - tau, 0.f, MAXW)};
        *(v4t*)(wme + wst) = w4;              // full projected w, my wave's copy
        w_own = __builtin_amdgcn_fmed3f(v_own - tau, 0.f, MAXW);
    }

    // ---- renormalize + store
    stage[0][tid] = w_own;
    __syncthreads();
    v4t w4 = *(const v4t*)(&stage[0][4 * lane]);
    float S = rdlane63(wave_sum63((w4.x + w4.y) + (w4.z + w4.w)));
    out[b * PP + tid] = w_own / (S + EPSF);
}

extern "C" void kernel_launch(void* const* d_in, const int* in_sizes, int n_in,
                              void* d_out, int out_size, void* d_ws, size_t ws_size,
                              hipStream_t stream) {
    const float* sigma  = (const float*)d_in[0];
    const float* beta   = (const float*)d_in[1];
    const float* wprevp = (const float*)d_in[2];
    const float* pl1    = (const float*)d_in[3];
    const float* pl2    = (const float*)d_in[4];
    float* outp = (float*)d_out;
    drb_kernel<<<dim3(512), dim3(256), 0, stream>>>(sigma, beta, wprevp, pl1, pl2, outp);
}

// Round 5
// 551.244 us; speedup vs baseline: 1.0683x; 1.0086x over previous
//
#include <hip/hip_runtime.h>
#include <math.h>

// DifferentiableRiskBudgeting: B=512, P=256. One block (256 thr) per batch.
// Thread (ti=tid>>2, tj=tid&3) owns rows 4ti..4ti+3 x cols 64tj..64tj+63.
//   Rows +0..2: fp32 VGPRs as <2 x float> pairs -> v_pk_fma_f32.
//   Row  +3: fp32 LDS slab, stride 272 + tj-stride 68 (conflict-free b128).
// Capacity note: 2 blocks/CU x (192 KB reg-sigma + 68 KB LDS slab) fills the
// 512 KB/CU RF + 160 KB LDS exactly -> 2 waves/SIMD is forced; occupancy is
// not a lever. The levers are VALU instruction count and chain latency.
// R7 (FAILED +4%), R8 (WIN -40%): warm-start Newton + |f|<=4e-6 early exit.
// R9 (NEUTRAL): chain fusion; R10 (WIN -5.5%): lean fast path.
// R11: VALUBusy implies ~520 instr/wave/iter vs ~190 static = x2.7 inflation
//   == the documented AGPR-move pathology (VGPR_Count=128 "tell" all
//   session). (a) __launch_bounds__(256,2) canonical min-waves decl;
//   (b) staging split into 4 sequential row loops to cut the peak pressure
//   where the AGPR spill of s0..s2 is born; (c) pseudo-random s_sleep skew
//   so co-resident blocks de-phase (chain stalls fill with matvec issue);
//   (d) setprio(1) on the post-barrier critical chain.

#define PP    256
#define MAXW  0.1f
#define EPSF  1e-8f
#define NPGD  250
#define NPOW  20
#define NILLMAX 10
#define FTOL  4e-6f

#define R3S   272   // sigma row-3 slab stride (floats); 272 % 32 == 16
#define TJS   68    // tj stride inside slab row;        68 % 32 == 4
#define WRDS  72    // w-copy block stride (64 data + 8 stagger)
#define VCOPY 280   // per-wave w copy stride

typedef float v2 __attribute__((ext_vector_type(2)));
typedef float v4t __attribute__((ext_vector_type(4)));

template<int CTRL>
__device__ __forceinline__ float dpp_zero(float x) {
    return __int_as_float(__builtin_amdgcn_update_dpp(
        0, __float_as_int(x), CTRL, 0xF, 0xF, true));
}
template<int CTRL>
__device__ __forceinline__ float dpp_keep(float x) {
    int xi = __float_as_int(x);
    return __int_as_float(__builtin_amdgcn_update_dpp(xi, xi, CTRL, 0xF, 0xF, false));
}
__device__ __forceinline__ float rdlane63(float x) {
    return __int_as_float(__builtin_amdgcn_readlane(__float_as_int(x), 63));
}
__device__ __forceinline__ float wave_sum63(float s) {
    s += dpp_zero<0x111>(s);
    s += dpp_zero<0x112>(s);
    s += dpp_zero<0x114>(s);
    s += dpp_zero<0x118>(s);
    s += dpp_zero<0x142>(s);
    s += dpp_zero<0x143>(s);
    return s;
}
__device__ __forceinline__ float wave_min63(float m) {
    m = fminf(m, dpp_keep<0x111>(m));
    m = fminf(m, dpp_keep<0x112>(m));
    m = fminf(m, dpp_keep<0x114>(m));
    m = fminf(m, dpp_keep<0x118>(m));
    m = fminf(m, dpp_keep<0x142>(m));
    m = fminf(m, dpp_keep<0x143>(m));
    return m;
}
__device__ __forceinline__ float wave_max63(float m) {
    m = fmaxf(m, dpp_keep<0x111>(m));
    m = fmaxf(m, dpp_keep<0x112>(m));
    m = fmaxf(m, dpp_keep<0x114>(m));
    m = fmaxf(m, dpp_keep<0x118>(m));
    m = fmaxf(m, dpp_keep<0x142>(m));
    m = fmaxf(m, dpp_keep<0x143>(m));
    return m;
}

__global__ __launch_bounds__(256, 2)
__attribute__((amdgpu_waves_per_eu(2, 2)))
#if __has_attribute(amdgpu_num_vgpr)
__attribute__((amdgpu_num_vgpr(256)))
#endif
#if __has_attribute(amdgpu_agpr_alloc)
__attribute__((amdgpu_agpr_alloc(0)))
#endif
void drb_kernel(const float* __restrict__ sigma,
                const float* __restrict__ beta,
                const float* __restrict__ wprev,
                const float* __restrict__ pl1,
                const float* __restrict__ pl2,
                float* __restrict__ out)
{
    const int b    = blockIdx.x;
    const int tid  = threadIdx.x;
    const int lane = tid & 63;
    const int wv   = tid >> 6;
    const int ti   = tid >> 2;   // 0..63
    const int tj   = tid & 3;    // 0..3

    __shared__ __align__(16) float sigR3[64 * R3S];   // 69632 B
    __shared__ __align__(16) float wcop[4 * VCOPY];   //  4480 B
    __shared__ __align__(16) float stage[2][256];     //  2048 B

    // ---- phase skew: de-phase the two co-resident blocks on each CU so one
    // block's matvec issue fills the other's projection-chain stalls.
    {
        unsigned h = (unsigned)b * 2654435761u;
        int sk = (h >> 28) & 3;
        for (int i = 0; i < sk; ++i) __builtin_amdgcn_s_sleep(7);
    }

    const float* Sb = sigma + (size_t)b * (PP * PP);

    // ---- stage sigma: rows +0..2 -> v2 VGPR pairs; row +3 -> LDS slab.
    // Sequential single-row loops: keep peak register pressure low so the
    // allocator never spills s0..s2 to AGPRs (the x2.7 VALU-inflation bug).
    v2 s0[32], s1[32], s2[32];
    {
        const float* r0 = Sb + (4 * ti + 0) * PP + 64 * tj;
#pragma unroll
        for (int k = 0; k < 16; ++k) {
            v4t t = *(const v4t*)(r0 + 4 * k);
            s0[2*k]   = __builtin_shufflevector(t, t, 0, 1);
            s0[2*k+1] = __builtin_shufflevector(t, t, 2, 3);
        }
    }
    {
        const float* r1 = Sb + (4 * ti + 1) * PP + 64 * tj;
#pragma unroll
        for (int k = 0; k < 16; ++k) {
            v4t t = *(const v4t*)(r1 + 4 * k);
            s1[2*k]   = __builtin_shufflevector(t, t, 0, 1);
            s1[2*k+1] = __builtin_shufflevector(t, t, 2, 3);
        }
    }
    {
        const float* r2 = Sb + (4 * ti + 2) * PP + 64 * tj;
#pragma unroll
        for (int k = 0; k < 16; ++k) {
            v4t t = *(const v4t*)(r2 + 4 * k);
            s2[2*k]   = __builtin_shufflevector(t, t, 0, 1);
            s2[2*k+1] = __builtin_shufflevector(t, t, 2, 3);
        }
    }
    {
        const float* r3 = Sb + (4 * ti + 3) * PP + 64 * tj;
        float* d3 = sigR3 + ti * R3S + TJS * tj;
#pragma unroll
        for (int k = 0; k < 16; ++k)
            *(v4t*)(d3 + 4 * k) = *(const v4t*)(r3 + 4 * k);
        // row-3 slab is written and read by the SAME thread -> no barrier.
    }

    const float bt   = beta[b * PP + tid];
    const float wp   = wprev[b * PP + tid];
    const float lam1 = expf(pl1[0]);
    const float lam2 = expf(pl2[0]);

    float* wme = wcop + wv * VCOPY;                // my wave's full-vector copy
    const int wst = 4 * lane + 8 * (lane >> 4);    // staggered write slot
    const float* wrd = wme + WRDS * tj;            // matvec read base (72*tj)

    // y = Sigma * w (w from my wave's copy); returns y[row tid]
    auto matvec = [&]() -> float {
        v2 y0 = {0.f, 0.f}, y1 = {0.f, 0.f}, y2 = {0.f, 0.f}, y3 = {0.f, 0.f};
        const float* p3 = sigR3 + ti * R3S + TJS * tj;
#pragma unroll
        for (int k = 0; k < 16; ++k) {
            v4t wq = *(const v4t*)(wrd + 4 * k);
            v2 w01 = __builtin_shufflevector(wq, wq, 0, 1);
            v2 w23 = __builtin_shufflevector(wq, wq, 2, 3);
            y0 = __builtin_elementwise_fma(s0[2*k],   w01, y0);
            y0 = __builtin_elementwise_fma(s0[2*k+1], w23, y0);
            y1 = __builtin_elementwise_fma(s1[2*k],   w01, y1);
            y1 = __builtin_elementwise_fma(s1[2*k+1], w23, y1);
            y2 = __builtin_elementwise_fma(s2[2*k],   w01, y2);
            y2 = __builtin_elementwise_fma(s2[2*k+1], w23, y2);
            v4t q = *(const v4t*)(p3 + 4 * k);
            v2 q01 = __builtin_shufflevector(q, q, 0, 1);
            v2 q23 = __builtin_shufflevector(q, q, 2, 3);
            y3 = __builtin_elementwise_fma(q01, w01, y3);
            y3 = __builtin_elementwise_fma(q23, w23, y3);
        }
        float r0 = y0.x + y0.y, r1 = y1.x + y1.y;
        float r2 = y2.x + y2.y, r3 = y3.x + y3.y;
        r0 += dpp_zero<0x4E>(r0); r1 += dpp_zero<0x4E>(r1);
        r2 += dpp_zero<0x4E>(r2); r3 += dpp_zero<0x4E>(r3);
        r0 += dpp_zero<0xB1>(r0); r1 += dpp_zero<0xB1>(r1);
        r2 += dpp_zero<0xB1>(r2); r3 += dpp_zero<0xB1>(r3);
        float a01 = (tj & 1) ? r1 : r0;
        float a23 = (tj & 1) ? r3 : r2;
        return (tj & 2) ? a23 : a01;
    };

    // ---- power iteration: each wave's copy initialized to 1/16 (wave-local)
    {
        v4t c = {0.0625f, 0.0625f, 0.0625f, 0.0625f};
        *(v4t*)(wme + wst) = c;
    }

    float y_last = 0.f, a_last = 1.f;
#pragma unroll 1
    for (int pi = 0; pi < NPOW; ++pi) {
        float y = matvec();
        stage[pi & 1][tid] = y;
        __syncthreads();
        v4t u4 = *(const v4t*)(&stage[pi & 1][4 * lane]);
        float ss = fmaf(u4.x, u4.x, fmaf(u4.y, u4.y, fmaf(u4.z, u4.z, u4.w * u4.w)));
        float a  = 1.f / (sqrtf(rdlane63(wave_sum63(ss))) + EPSF);
        v4t n4 = {a * u4.x, a * u4.y, a * u4.z, a * u4.w};
        *(v4t*)(wme + wst) = n4;          // full normalized vector, my copy
        y_last = y; a_last = a;
    }

    // ---- lmax = v' S v ; step
    float stepf;
    {
        float ysv = matvec();
        float p   = (a_last * y_last) * ysv;
        stage[0][tid] = p;
        __syncthreads();
        v4t p4 = *(const v4t*)(&stage[0][4 * lane]);
        float lmax = rdlane63(wave_sum63((p4.x + p4.y) + (p4.z + p4.w)));
        stepf = 1.f / (2.f * lmax + 2.f * lam2 + 1e-6f);
        __syncthreads();   // everyone done with stage[0] before PGD reuses it
    }

    // ---- PGD init: w0 = 1/256 (wave-local full copy)
    float w_own = 1.f / 256.f;
    {
        v4t c = {1.f/256.f, 1.f/256.f, 1.f/256.f, 1.f/256.f};
        *(v4t*)(wme + wst) = c;
    }
    const float Ac = 1.f - 2.f * lam2 * stepf;
    const float Bc = -2.f * stepf;
    const float Cc = stepf * (bt - lam1 + 2.f * lam2 * wp);

    float tau_pred = 0.f;   // warm-start/extrapolated probe for next iter
    float tau_last = 0.f;   // tau of previous iteration
    float dtau_last = 0.f;  // previous tau delta (for Aitken)

#pragma unroll 1
    for (int it = 0; it < NPGD; ++it) {
        float y = matvec();
        float v_own = fmaf(w_own, Ac, fmaf(y, Bc, Cc));
        const int sb = it & 1;
        stage[sb][tid] = v_own;
        __syncthreads();                      // the ONLY barrier this iteration

        __builtin_amdgcn_s_setprio(1);        // critical chain: win issue slots
        v4t v4 = *(const v4t*)(&stage[sb][4 * lane]);

        // ---- FAST PATH: evaluate only f(tau_pred) — a single S-chain.
        float tau = tau_pred;
        {
            float d0 = v4.x - tau, d1 = v4.y - tau;
            float d2 = v4.z - tau, d3 = v4.w - tau;
            float c0 = __builtin_amdgcn_fmed3f(d0, 0.f, MAXW);
            float c1 = __builtin_amdgcn_fmed3f(d1, 0.f, MAXW);
            float c2 = __builtin_amdgcn_fmed3f(d2, 0.f, MAXW);
            float c3 = __builtin_amdgcn_fmed3f(d3, 0.f, MAXW);
            float Sw = wave_sum63((c0 + c1) + (c2 + c3));
            float f  = rdlane63(Sw) - 1.f;

            if (!(fabsf(f) <= FTOL)) {        // uniform scalar branch
                // ---- SLOW PATH: build bracket (mn/mx) + count at tau.
                float mnl = fminf(fminf(v4.x, v4.y), fminf(v4.z, v4.w));
                float mxl = fmaxf(fmaxf(v4.x, v4.y), fmaxf(v4.z, v4.w));
                float n0 = ((d0 > 0.f) & (d0 < MAXW)) ? 1.f : 0.f;
                float n1 = ((d1 > 0.f) & (d1 < MAXW)) ? 1.f : 0.f;
                float n2 = ((d2 > 0.f) & (d2 < MAXW)) ? 1.f : 0.f;
                float n3 = ((d3 > 0.f) & (d3 < MAXW)) ? 1.f : 0.f;
                float mnw = wave_min63(mnl);
                float mxw = wave_max63(mxl);
                float Nw  = wave_sum63((n0 + n1) + (n2 + n3));
                float mn  = rdlane63(mnw);
                float mx  = rdlane63(mxw);
                float cnt = rdlane63(Nw);
                // Bracket init from known values:
                //   f(mn-MAXW)=256*MAXW-1 (>0),  f(mx)=-1 (<0), plus eval#1.
                bool pos0 = f > 0.f;
                float lo  = pos0 ? tau : mn - MAXW;
                float flo = pos0 ? f   : 256.f * MAXW - 1.f;
                float hi  = pos0 ? mx  : tau;
                float fhi = pos0 ? -1.f : f;
                int side  = pos0 ? 1 : -1;
#pragma unroll 1
                for (int r = 1; r < NILLMAX; ++r) {
                    // Newton (exact on current linear segment); Illinois
                    // secant fallback when out-of-bracket / cnt==0 / NaN.
                    float tn = fmaf(f, __builtin_amdgcn_rcpf(cnt), tau);
                    float ts = (lo * fhi - hi * flo) *
                               __builtin_amdgcn_rcpf(fhi - flo);
                    bool good = (tn > lo) & (tn < hi);
                    tau = good ? tn : ts;
                    float e0 = v4.x - tau, e1 = v4.y - tau;
                    float e2 = v4.z - tau, e3 = v4.w - tau;
                    float g0 = __builtin_amdgcn_fmed3f(e0, 0.f, MAXW);
                    float g1 = __builtin_amdgcn_fmed3f(e1, 0.f, MAXW);
                    float g2 = __builtin_amdgcn_fmed3f(e2, 0.f, MAXW);
                    float g3 = __builtin_amdgcn_fmed3f(e3, 0.f, MAXW);
                    float m0 = ((e0 > 0.f) & (e0 < MAXW)) ? 1.f : 0.f;
                    float m1 = ((e1 > 0.f) & (e1 < MAXW)) ? 1.f : 0.f;
                    float m2 = ((e2 > 0.f) & (e2 < MAXW)) ? 1.f : 0.f;
                    float m3 = ((e3 > 0.f) & (e3 < MAXW)) ? 1.f : 0.f;
                    float Sr = wave_sum63((g0 + g1) + (g2 + g3));
                    float Nr = wave_sum63((m0 + m1) + (m2 + m3));
                    f   = rdlane63(Sr) - 1.f;
                    cnt = rdlane63(Nr);
                    if (fabsf(f) <= FTOL) break;  // uniform
                    bool pos = f > 0.f;
                    float nflo = pos ? f   : ((side < 0) ? 0.5f * flo : flo);
                    float nfhi = pos ? ((side > 0) ? 0.5f * fhi : fhi) : f;
                    lo  = pos ? tau : lo;
                    hi  = pos ? hi  : tau;
                    flo = nflo; fhi = nfhi;
                    side = pos ? 1 : -1;
                }
            }
        }

        // ---- Aitken predictor (uniform, off critical path): tau drifts
        // geometrically near the PGD fixed point; extrapolate the limit.
        {
            float dtau = tau - tau_last;
            float rho  = dtau * __builtin_amdgcn_rcpf(dtau_last);
            bool okx = (fabsf(dtau_last) > 1e-20f) & (rho > 0.f) &
                       (rho < 0.9f) & (fabsf(dtau) < 1e-2f);
            float extr = okx ? dtau * rho * __builtin_amdgcn_rcpf(1.f - rho) : 0.f;
            tau_pred = tau + extr;
            tau_last = tau;
            dtau_last = dtau;
        }

        v4t w4 = {__builtin_amdgcn_fmed3f(v4.x - tau, 0.f, MAXW),
                  __builtin_amdgcn_fmed3f(v4.y - tau, 0.f, MAXW),
                  __builtin_amdgcn_fmed3f(v4.z - tau, 0.f, MAXW),
                  __builtin_amdgcn_fmed3f(v4.w - tau, 0.f, MAXW)};
        *(v4t*)(wme + wst) = w4;              // full projected w, my wave's copy
        __builtin_amdgcn_s_setprio(0);        // back to throughput phase
        w_own = __builtin_amdgcn_fmed3f(v_own - tau, 0.f, MAXW);
    }

    // ---- renormalize + store
    stage[0][tid] = w_own;
    __syncthreads();
    v4t w4 = *(const v4t*)(&stage[0][4 * lane]);
    float S = rdlane63(wave_sum63((w4.x + w4.y) + (w4.z + w4.w)));
    out[b * PP + tid] = w_own / (S + EPSF);
}

extern "C" void kernel_launch(void* const* d_in, const int* in_sizes, int n_in,
                              void* d_out, int out_size, void* d_ws, size_t ws_size,
                              hipStream_t stream) {
    const float* sigma  = (const float*)d_in[0];
    const float* beta   = (const float*)d_in[1];
    const float* wprevp = (const float*)d_in[2];
    const float* pl1    = (const float*)d_in[3];
    const float* pl2    = (const float*)d_in[4];
    float* outp = (float*)d_out;
    drb_kernel<<<dim3(512), dim3(256), 0, stream>>>(sigma, beta, wprevp, pl1, pl2, outp);
}

// Round 6
// 330.250 us; speedup vs baseline: 1.7832x; 1.6692x over previous
//
#include <hip/hip_runtime.h>
#include <math.h>

// DifferentiableRiskBudgeting: B=512, P=256. One block (256 thr) per batch.
// Thread (ti=tid>>2, tj=tid&3) owns rows 4ti..4ti+3 x cols 64tj..64tj+63.
//   Rows +0..2: fp32 VGPRs as <2 x float> pairs -> v_pk_fma_f32.
//   Row  +3: fp32 LDS slab, stride 272 + tj-stride 68 (conflict-free b128).
// Capacity: 2 blocks/CU fills RF+LDS; occupancy is not a lever.
// R7 (FAILED +4%); R8 (WIN -40%): warm-start Newton + |f|<=4e-6 early exit.
// R9 (NEUTRAL); R10 (WIN -5.5%): lean fast path. R11 (NULL): AGPR-attack
//   attrs + skew + setprio — VGPR_Count pinned at 128, VALUBusy unmoved.
//   AGPR theory retired (pk_fma is likely half-rate; AGPR-direct operands).
// R12: wall 4060 cyc/iter vs ~2110 VALU busy/SIMD => 48% dual-wave stall.
//   (a) matvec ILP: split y0..y3 (four 32-deep dep chains) into 8 even/odd
//       chains -> dep latency fully covered, co-stall shrinks.
//   (b) rigorous early stop: PGD map is a contraction (proj nonexpansive),
//       delta_t = max|dw| monotone; ||w_250 - w_k||inf <= (250-k)*delta_k.
//       Stop when delta < 1e-7 on two consecutive iters (uniform across
//       waves; dmax chain off critical path, checked one iter late).
//       Added error <= 2.5e-5 << current absmax 2.44e-4. Barrier added
//       before final stage[0] write (exit parity now data-dependent).

#define PP    256
#define MAXW  0.1f
#define EPSF  1e-8f
#define NPGD  250
#define NPOW  20
#define NILLMAX 10
#define FTOL  4e-6f
#define STOPTOL 1e-7f
#define MINIT 48

#define R3S   272   // sigma row-3 slab stride (floats); 272 % 32 == 16
#define TJS   68    // tj stride inside slab row;        68 % 32 == 4
#define WRDS  72    // w-copy block stride (64 data + 8 stagger)
#define VCOPY 280   // per-wave w copy stride

typedef float v2 __attribute__((ext_vector_type(2)));
typedef float v4t __attribute__((ext_vector_type(4)));

template<int CTRL>
__device__ __forceinline__ float dpp_zero(float x) {
    return __int_as_float(__builtin_amdgcn_update_dpp(
        0, __float_as_int(x), CTRL, 0xF, 0xF, true));
}
template<int CTRL>
__device__ __forceinline__ float dpp_keep(float x) {
    int xi = __float_as_int(x);
    return __int_as_float(__builtin_amdgcn_update_dpp(xi, xi, CTRL, 0xF, 0xF, false));
}
__device__ __forceinline__ float rdlane63(float x) {
    return __int_as_float(__builtin_amdgcn_readlane(__float_as_int(x), 63));
}
__device__ __forceinline__ float wave_sum63(float s) {
    s += dpp_zero<0x111>(s);
    s += dpp_zero<0x112>(s);
    s += dpp_zero<0x114>(s);
    s += dpp_zero<0x118>(s);
    s += dpp_zero<0x142>(s);
    s += dpp_zero<0x143>(s);
    return s;
}
__device__ __forceinline__ float wave_min63(float m) {
    m = fminf(m, dpp_keep<0x111>(m));
    m = fminf(m, dpp_keep<0x112>(m));
    m = fminf(m, dpp_keep<0x114>(m));
    m = fminf(m, dpp_keep<0x118>(m));
    m = fminf(m, dpp_keep<0x142>(m));
    m = fminf(m, dpp_keep<0x143>(m));
    return m;
}
__device__ __forceinline__ float wave_max63(float m) {
    m = fmaxf(m, dpp_keep<0x111>(m));
    m = fmaxf(m, dpp_keep<0x112>(m));
    m = fmaxf(m, dpp_keep<0x114>(m));
    m = fmaxf(m, dpp_keep<0x118>(m));
    m = fmaxf(m, dpp_keep<0x142>(m));
    m = fmaxf(m, dpp_keep<0x143>(m));
    return m;
}

__global__ __launch_bounds__(256, 2)
__attribute__((amdgpu_waves_per_eu(2, 2)))
void drb_kernel(const float* __restrict__ sigma,
                const float* __restrict__ beta,
                const float* __restrict__ wprev,
                const float* __restrict__ pl1,
                const float* __restrict__ pl2,
                float* __restrict__ out)
{
    const int b    = blockIdx.x;
    const int tid  = threadIdx.x;
    const int lane = tid & 63;
    const int wv   = tid >> 6;
    const int ti   = tid >> 2;   // 0..63
    const int tj   = tid & 3;    // 0..3

    __shared__ __align__(16) float sigR3[64 * R3S];   // 69632 B
    __shared__ __align__(16) float wcop[4 * VCOPY];   //  4480 B
    __shared__ __align__(16) float stage[2][256];     //  2048 B

    const float* Sb = sigma + (size_t)b * (PP * PP);

    // ---- stage sigma: rows +0..2 -> v2 VGPR pairs; row +3 -> LDS slab.
    v2 s0[32], s1[32], s2[32];
    {
        const float* r0 = Sb + (4 * ti + 0) * PP + 64 * tj;
#pragma unroll
        for (int k = 0; k < 16; ++k) {
            v4t t = *(const v4t*)(r0 + 4 * k);
            s0[2*k]   = __builtin_shufflevector(t, t, 0, 1);
            s0[2*k+1] = __builtin_shufflevector(t, t, 2, 3);
        }
    }
    {
        const float* r1 = Sb + (4 * ti + 1) * PP + 64 * tj;
#pragma unroll
        for (int k = 0; k < 16; ++k) {
            v4t t = *(const v4t*)(r1 + 4 * k);
            s1[2*k]   = __builtin_shufflevector(t, t, 0, 1);
            s1[2*k+1] = __builtin_shufflevector(t, t, 2, 3);
        }
    }
    {
        const float* r2 = Sb + (4 * ti + 2) * PP + 64 * tj;
#pragma unroll
        for (int k = 0; k < 16; ++k) {
            v4t t = *(const v4t*)(r2 + 4 * k);
            s2[2*k]   = __builtin_shufflevector(t, t, 0, 1);
            s2[2*k+1] = __builtin_shufflevector(t, t, 2, 3);
        }
    }
    {
        const float* r3 = Sb + (4 * ti + 3) * PP + 64 * tj;
        float* d3 = sigR3 + ti * R3S + TJS * tj;
#pragma unroll
        for (int k = 0; k < 16; ++k)
            *(v4t*)(d3 + 4 * k) = *(const v4t*)(r3 + 4 * k);
        // row-3 slab is written and read by the SAME thread -> no barrier.
    }

    const float bt   = beta[b * PP + tid];
    const float wp   = wprev[b * PP + tid];
    const float lam1 = expf(pl1[0]);
    const float lam2 = expf(pl2[0]);

    float* wme = wcop + wv * VCOPY;                // my wave's full-vector copy
    const int wst = 4 * lane + 8 * (lane >> 4);    // staggered write slot
    const float* wrd = wme + WRDS * tj;            // matvec read base (72*tj)

    // y = Sigma * w (w from my wave's copy); returns y[row tid].
    // 8 independent accumulator chains (even/odd k) so FMA dep latency is
    // fully covered by issue rotation.
    auto matvec = [&]() -> float {
        v2 y0a = {0.f, 0.f}, y0b = {0.f, 0.f};
        v2 y1a = {0.f, 0.f}, y1b = {0.f, 0.f};
        v2 y2a = {0.f, 0.f}, y2b = {0.f, 0.f};
        v2 y3a = {0.f, 0.f}, y3b = {0.f, 0.f};
        const float* p3 = sigR3 + ti * R3S + TJS * tj;
#pragma unroll
        for (int k = 0; k < 16; ++k) {
            v4t wq = *(const v4t*)(wrd + 4 * k);
            v2 w01 = __builtin_shufflevector(wq, wq, 0, 1);
            v2 w23 = __builtin_shufflevector(wq, wq, 2, 3);
            y0a = __builtin_elementwise_fma(s0[2*k],   w01, y0a);
            y0b = __builtin_elementwise_fma(s0[2*k+1], w23, y0b);
            y1a = __builtin_elementwise_fma(s1[2*k],   w01, y1a);
            y1b = __builtin_elementwise_fma(s1[2*k+1], w23, y1b);
            y2a = __builtin_elementwise_fma(s2[2*k],   w01, y2a);
            y2b = __builtin_elementwise_fma(s2[2*k+1], w23, y2b);
            v4t q = *(const v4t*)(p3 + 4 * k);
            v2 q01 = __builtin_shufflevector(q, q, 0, 1);
            v2 q23 = __builtin_shufflevector(q, q, 2, 3);
            y3a = __builtin_elementwise_fma(q01, w01, y3a);
            y3b = __builtin_elementwise_fma(q23, w23, y3b);
        }
        float r0 = (y0a.x + y0a.y) + (y0b.x + y0b.y);
        float r1 = (y1a.x + y1a.y) + (y1b.x + y1b.y);
        float r2 = (y2a.x + y2a.y) + (y2b.x + y2b.y);
        float r3 = (y3a.x + y3a.y) + (y3b.x + y3b.y);
        r0 += dpp_zero<0x4E>(r0); r1 += dpp_zero<0x4E>(r1);
        r2 += dpp_zero<0x4E>(r2); r3 += dpp_zero<0x4E>(r3);
        r0 += dpp_zero<0xB1>(r0); r1 += dpp_zero<0xB1>(r1);
        r2 += dpp_zero<0xB1>(r2); r3 += dpp_zero<0xB1>(r3);
        float a01 = (tj & 1) ? r1 : r0;
        float a23 = (tj & 1) ? r3 : r2;
        return (tj & 2) ? a23 : a01;
    };

    // ---- power iteration: each wave's copy initialized to 1/16 (wave-local)
    {
        v4t c = {0.0625f, 0.0625f, 0.0625f, 0.0625f};
        *(v4t*)(wme + wst) = c;
    }

    float y_last = 0.f, a_last = 1.f;
#pragma unroll 1
    for (int pi = 0; pi < NPOW; ++pi) {
        float y = matvec();
        stage[pi & 1][tid] = y;
        __syncthreads();
        v4t u4 = *(const v4t*)(&stage[pi & 1][4 * lane]);
        float ss = fmaf(u4.x, u4.x, fmaf(u4.y, u4.y, fmaf(u4.z, u4.z, u4.w * u4.w)));
        float a  = 1.f / (sqrtf(rdlane63(wave_sum63(ss))) + EPSF);
        v4t n4 = {a * u4.x, a * u4.y, a * u4.z, a * u4.w};
        *(v4t*)(wme + wst) = n4;          // full normalized vector, my copy
        y_last = y; a_last = a;
    }

    // ---- lmax = v' S v ; step
    float stepf;
    {
        float ysv = matvec();
        float p   = (a_last * y_last) * ysv;
        stage[0][tid] = p;
        __syncthreads();
        v4t p4 = *(const v4t*)(&stage[0][4 * lane]);
        float lmax = rdlane63(wave_sum63((p4.x + p4.y) + (p4.z + p4.w)));
        stepf = 1.f / (2.f * lmax + 2.f * lam2 + 1e-6f);
        __syncthreads();   // everyone done with stage[0] before PGD reuses it
    }

    // ---- PGD init: w0 = 1/256 (wave-local full copy)
    float w_own = 1.f / 256.f;
    {
        v4t c = {1.f/256.f, 1.f/256.f, 1.f/256.f, 1.f/256.f};
        *(v4t*)(wme + wst) = c;
    }
    const float Ac = 1.f - 2.f * lam2 * stepf;
    const float Bc = -2.f * stepf;
    const float Cc = stepf * (bt - lam1 + 2.f * lam2 * wp);

    float tau_pred = 0.f;   // warm-start/extrapolated probe for next iter
    float tau_last = 0.f;   // tau of previous iteration
    float dtau_last = 0.f;  // previous tau delta (for Aitken)

    v4t w4_prev = {1.f/256.f, 1.f/256.f, 1.f/256.f, 1.f/256.f};
    float dm1 = 1.f, dm2 = 1.f;   // last two max|dw| (uniform across waves)

#pragma unroll 1
    for (int it = 0; it < NPGD; ++it) {
        // uniform early stop: contraction => ||w_250 - w_k|| <= (250-k)*dmax
        if (it >= MINIT && dm1 < STOPTOL && dm2 < STOPTOL) break;

        float y = matvec();
        float v_own = fmaf(w_own, Ac, fmaf(y, Bc, Cc));
        const int sb = it & 1;
        stage[sb][tid] = v_own;
        __syncthreads();                      // the ONLY barrier this iteration

        __builtin_amdgcn_s_setprio(1);        // critical chain: win issue slots
        v4t v4 = *(const v4t*)(&stage[sb][4 * lane]);

        // ---- FAST PATH: evaluate only f(tau_pred) — a single S-chain.
        float tau = tau_pred;
        {
            float d0 = v4.x - tau, d1 = v4.y - tau;
            float d2 = v4.z - tau, d3 = v4.w - tau;
            float c0 = __builtin_amdgcn_fmed3f(d0, 0.f, MAXW);
            float c1 = __builtin_amdgcn_fmed3f(d1, 0.f, MAXW);
            float c2 = __builtin_amdgcn_fmed3f(d2, 0.f, MAXW);
            float c3 = __builtin_amdgcn_fmed3f(d3, 0.f, MAXW);
            float Sw = wave_sum63((c0 + c1) + (c2 + c3));
            float f  = rdlane63(Sw) - 1.f;

            if (!(fabsf(f) <= FTOL)) {        // uniform scalar branch
                // ---- SLOW PATH: build bracket (mn/mx) + count at tau.
                float mnl = fminf(fminf(v4.x, v4.y), fminf(v4.z, v4.w));
                float mxl = fmaxf(fmaxf(v4.x, v4.y), fmaxf(v4.z, v4.w));
                float n0 = ((d0 > 0.f) & (d0 < MAXW)) ? 1.f : 0.f;
                float n1 = ((d1 > 0.f) & (d1 < MAXW)) ? 1.f : 0.f;
                float n2 = ((d2 > 0.f) & (d2 < MAXW)) ? 1.f : 0.f;
                float n3 = ((d3 > 0.f) & (d3 < MAXW)) ? 1.f : 0.f;
                float mnw = wave_min63(mnl);
                float mxw = wave_max63(mxl);
                float Nw  = wave_sum63((n0 + n1) + (n2 + n3));
                float mn  = rdlane63(mnw);
                float mx  = rdlane63(mxw);
                float cnt = rdlane63(Nw);
                // Bracket init from known values:
                //   f(mn-MAXW)=256*MAXW-1 (>0),  f(mx)=-1 (<0), plus eval#1.
                bool pos0 = f > 0.f;
                float lo  = pos0 ? tau : mn - MAXW;
                float flo = pos0 ? f   : 256.f * MAXW - 1.f;
                float hi  = pos0 ? mx  : tau;
                float fhi = pos0 ? -1.f : f;
                int side  = pos0 ? 1 : -1;
#pragma unroll 1
                for (int r = 1; r < NILLMAX; ++r) {
                    // Newton (exact on current linear segment); Illinois
                    // secant fallback when out-of-bracket / cnt==0 / NaN.
                    float tn = fmaf(f, __builtin_amdgcn_rcpf(cnt), tau);
                    float ts = (lo * fhi - hi * flo) *
                               __builtin_amdgcn_rcpf(fhi - flo);
                    bool good = (tn > lo) & (tn < hi);
                    tau = good ? tn : ts;
                    float e0 = v4.x - tau, e1 = v4.y - tau;
                    float e2 = v4.z - tau, e3 = v4.w - tau;
                    float g0 = __builtin_amdgcn_fmed3f(e0, 0.f, MAXW);
                    float g1 = __builtin_amdgcn_fmed3f(e1, 0.f, MAXW);
                    float g2 = __builtin_amdgcn_fmed3f(e2, 0.f, MAXW);
                    float g3 = __builtin_amdgcn_fmed3f(e3, 0.f, MAXW);
                    float m0 = ((e0 > 0.f) & (e0 < MAXW)) ? 1.f : 0.f;
                    float m1 = ((e1 > 0.f) & (e1 < MAXW)) ? 1.f : 0.f;
                    float m2 = ((e2 > 0.f) & (e2 < MAXW)) ? 1.f : 0.f;
                    float m3 = ((e3 > 0.f) & (e3 < MAXW)) ? 1.f : 0.f;
                    float Sr = wave_sum63((g0 + g1) + (g2 + g3));
                    float Nr = wave_sum63((m0 + m1) + (m2 + m3));
                    f   = rdlane63(Sr) - 1.f;
                    cnt = rdlane63(Nr);
                    if (fabsf(f) <= FTOL) break;  // uniform
                    bool pos = f > 0.f;
                    float nflo = pos ? f   : ((side < 0) ? 0.5f * flo : flo);
                    float nfhi = pos ? ((side > 0) ? 0.5f * fhi : fhi) : f;
                    lo  = pos ? tau : lo;
                    hi  = pos ? hi  : tau;
                    flo = nflo; fhi = nfhi;
                    side = pos ? 1 : -1;
                }
            }
        }

        // ---- Aitken predictor (uniform, off critical path)
        {
            float dtau = tau - tau_last;
            float rho  = dtau * __builtin_amdgcn_rcpf(dtau_last);
            bool okx = (fabsf(dtau_last) > 1e-20f) & (rho > 0.f) &
                       (rho < 0.9f) & (fabsf(dtau) < 1e-2f);
            float extr = okx ? dtau * rho * __builtin_amdgcn_rcpf(1.f - rho) : 0.f;
            tau_pred = tau + extr;
            tau_last = tau;
            dtau_last = dtau;
        }

        v4t w4 = {__builtin_amdgcn_fmed3f(v4.x - tau, 0.f, MAXW),
                  __builtin_amdgcn_fmed3f(v4.y - tau, 0.f, MAXW),
                  __builtin_amdgcn_fmed3f(v4.z - tau, 0.f, MAXW),
                  __builtin_amdgcn_fmed3f(v4.w - tau, 0.f, MAXW)};
        *(v4t*)(wme + wst) = w4;              // full projected w, my wave's copy
        __builtin_amdgcn_s_setprio(0);        // back to throughput phase
        w_own = __builtin_amdgcn_fmed3f(v_own - tau, 0.f, MAXW);

        // ---- max|dw| chain, off critical path (overlaps next matvec issue);
        // consumed one iteration later at the loop-top uniform break.
        {
            float pm = fmaxf(fmaxf(fabsf(w4.x - w4_prev.x),
                                   fabsf(w4.y - w4_prev.y)),
                             fmaxf(fabsf(w4.z - w4_prev.z),
                                   fabsf(w4.w - w4_prev.w)));
            w4_prev = w4;
            dm2 = dm1;
            dm1 = rdlane63(wave_max63(pm));
        }
    }

    // ---- renormalize + store (barrier first: exit parity is data-dependent)
    __syncthreads();
    stage[0][tid] = w_own;
    __syncthreads();
    v4t w4 = *(const v4t*)(&stage[0][4 * lane]);
    float S = rdlane63(wave_sum63((w4.x + w4.y) + (w4.z + w4.w)));
    out[b * PP + tid] = w_own / (S + EPSF);
}

extern "C" void kernel_launch(void* const* d_in, const int* in_sizes, int n_in,
                              void* d_out, int out_size, void* d_ws, size_t ws_size,
                              hipStream_t stream) {
    const float* sigma  = (const float*)d_in[0];
    const float* beta   = (const float*)d_in[1];
    const float* wprevp = (const float*)d_in[2];
    const float* pl1    = (const float*)d_in[3];
    const float* pl2    = (const float*)d_in[4];
    float* outp = (float*)d_out;
    drb_kernel<<<dim3(512), dim3(256), 0, stream>>>(sigma, beta, wprevp, pl1, pl2, outp);
}

// Round 7
// 304.301 us; speedup vs baseline: 1.9353x; 1.0853x over previous
//
#include <hip/hip_runtime.h>
#include <math.h>

// DifferentiableRiskBudgeting: B=512, P=256. One block (256 thr) per batch.
// Thread (ti=tid>>2, tj=tid&3) owns rows 4ti..4ti+3 x cols 64tj..64tj+63.
//   Rows +0..2: fp32 VGPRs as <2 x float> pairs -> v_pk_fma_f32.
//   Row  +3: fp32 LDS slab, stride 272 + tj-stride 68 (conflict-free b128).
// Capacity: 2 blocks/CU fills RF+LDS; occupancy is not a lever.
// R8 (WIN -40%): warm-start Newton + early exit. R10 (WIN -5.5%): lean fast
// path. R11 (NULL): AGPR attrs/skew/setprio. R12 (WIN -57%): 8-chain matvec
// ILP + rigorous early stop (dm<1e-7 x2) — absmax BIT-IDENTICAL => PGD is
// fully converged <<250 iters; reference's w_250 == fixed point. License:
// only the fixed point matters (unique minimizer, strongly convex QP).
// R13: Nesterov momentum. mu >= 2*lam2+2e-3 certified (sigma >= 1e-3 I);
//   L_safe = 1.15 * (2*lmax_RQ + 2*lam2) (RQ underestimates lmax on the MP
//   edge; momentum needs step <= 1/L_true). beta = (1-q)/(1+q), q=sqrt(mu/L).
//   Restart heuristic: dm growing (dm1>1.2*dm2) => beta=0 that iter (uniform
//   scalars, already computed) — worst case degrades to plain PGD. NPGD cap
//   kept. Expected sqrt(kappa)~5x fewer iters on the quadratic phase.

#define PP    256
#define MAXW  0.1f
#define EPSF  1e-8f
#define NPGD  250
#define NPOW  20
#define NILLMAX 10
#define FTOL  4e-6f
#define STOPTOL 1e-7f
#define MINIT 24

#define R3S   272   // sigma row-3 slab stride (floats); 272 % 32 == 16
#define TJS   68    // tj stride inside slab row;        68 % 32 == 4
#define WRDS  72    // w-copy block stride (64 data + 8 stagger)
#define VCOPY 280   // per-wave w copy stride

typedef float v2 __attribute__((ext_vector_type(2)));
typedef float v4t __attribute__((ext_vector_type(4)));

template<int CTRL>
__device__ __forceinline__ float dpp_zero(float x) {
    return __int_as_float(__builtin_amdgcn_update_dpp(
        0, __float_as_int(x), CTRL, 0xF, 0xF, true));
}
template<int CTRL>
__device__ __forceinline__ float dpp_keep(float x) {
    int xi = __float_as_int(x);
    return __int_as_float(__builtin_amdgcn_update_dpp(xi, xi, CTRL, 0xF, 0xF, false));
}
__device__ __forceinline__ float rdlane63(float x) {
    return __int_as_float(__builtin_amdgcn_readlane(__float_as_int(x), 63));
}
__device__ __forceinline__ float wave_sum63(float s) {
    s += dpp_zero<0x111>(s);
    s += dpp_zero<0x112>(s);
    s += dpp_zero<0x114>(s);
    s += dpp_zero<0x118>(s);
    s += dpp_zero<0x142>(s);
    s += dpp_zero<0x143>(s);
    return s;
}
__device__ __forceinline__ float wave_min63(float m) {
    m = fminf(m, dpp_keep<0x111>(m));
    m = fminf(m, dpp_keep<0x112>(m));
    m = fminf(m, dpp_keep<0x114>(m));
    m = fminf(m, dpp_keep<0x118>(m));
    m = fminf(m, dpp_keep<0x142>(m));
    m = fminf(m, dpp_keep<0x143>(m));
    return m;
}
__device__ __forceinline__ float wave_max63(float m) {
    m = fmaxf(m, dpp_keep<0x111>(m));
    m = fmaxf(m, dpp_keep<0x112>(m));
    m = fmaxf(m, dpp_keep<0x114>(m));
    m = fmaxf(m, dpp_keep<0x118>(m));
    m = fmaxf(m, dpp_keep<0x142>(m));
    m = fmaxf(m, dpp_keep<0x143>(m));
    return m;
}

__global__ __launch_bounds__(256, 2)
__attribute__((amdgpu_waves_per_eu(2, 2)))
void drb_kernel(const float* __restrict__ sigma,
                const float* __restrict__ beta,
                const float* __restrict__ wprev,
                const float* __restrict__ pl1,
                const float* __restrict__ pl2,
                float* __restrict__ out)
{
    const int b    = blockIdx.x;
    const int tid  = threadIdx.x;
    const int lane = tid & 63;
    const int wv   = tid >> 6;
    const int ti   = tid >> 2;   // 0..63
    const int tj   = tid & 3;    // 0..3

    __shared__ __align__(16) float sigR3[64 * R3S];   // 69632 B
    __shared__ __align__(16) float wcop[4 * VCOPY];   //  4480 B
    __shared__ __align__(16) float stage[2][256];     //  2048 B

    const float* Sb = sigma + (size_t)b * (PP * PP);

    // ---- stage sigma: rows +0..2 -> v2 VGPR pairs; row +3 -> LDS slab.
    v2 s0[32], s1[32], s2[32];
    {
        const float* r0 = Sb + (4 * ti + 0) * PP + 64 * tj;
#pragma unroll
        for (int k = 0; k < 16; ++k) {
            v4t t = *(const v4t*)(r0 + 4 * k);
            s0[2*k]   = __builtin_shufflevector(t, t, 0, 1);
            s0[2*k+1] = __builtin_shufflevector(t, t, 2, 3);
        }
    }
    {
        const float* r1 = Sb + (4 * ti + 1) * PP + 64 * tj;
#pragma unroll
        for (int k = 0; k < 16; ++k) {
            v4t t = *(const v4t*)(r1 + 4 * k);
            s1[2*k]   = __builtin_shufflevector(t, t, 0, 1);
            s1[2*k+1] = __builtin_shufflevector(t, t, 2, 3);
        }
    }
    {
        const float* r2 = Sb + (4 * ti + 2) * PP + 64 * tj;
#pragma unroll
        for (int k = 0; k < 16; ++k) {
            v4t t = *(const v4t*)(r2 + 4 * k);
            s2[2*k]   = __builtin_shufflevector(t, t, 0, 1);
            s2[2*k+1] = __builtin_shufflevector(t, t, 2, 3);
        }
    }
    {
        const float* r3 = Sb + (4 * ti + 3) * PP + 64 * tj;
        float* d3 = sigR3 + ti * R3S + TJS * tj;
#pragma unroll
        for (int k = 0; k < 16; ++k)
            *(v4t*)(d3 + 4 * k) = *(const v4t*)(r3 + 4 * k);
        // row-3 slab is written and read by the SAME thread -> no barrier.
    }

    const float bt   = beta[b * PP + tid];
    const float wp   = wprev[b * PP + tid];
    const float lam1 = expf(pl1[0]);
    const float lam2 = expf(pl2[0]);

    float* wme = wcop + wv * VCOPY;                // my wave's full-vector copy
    const int wst = 4 * lane + 8 * (lane >> 4);    // staggered write slot
    const float* wrd = wme + WRDS * tj;            // matvec read base (72*tj)

    // y = Sigma * z (z from my wave's copy); returns y[row tid].
    // 8 independent accumulator chains (even/odd k).
    auto matvec = [&]() -> float {
        v2 y0a = {0.f, 0.f}, y0b = {0.f, 0.f};
        v2 y1a = {0.f, 0.f}, y1b = {0.f, 0.f};
        v2 y2a = {0.f, 0.f}, y2b = {0.f, 0.f};
        v2 y3a = {0.f, 0.f}, y3b = {0.f, 0.f};
        const float* p3 = sigR3 + ti * R3S + TJS * tj;
#pragma unroll
        for (int k = 0; k < 16; ++k) {
            v4t wq = *(const v4t*)(wrd + 4 * k);
            v2 w01 = __builtin_shufflevector(wq, wq, 0, 1);
            v2 w23 = __builtin_shufflevector(wq, wq, 2, 3);
            y0a = __builtin_elementwise_fma(s0[2*k],   w01, y0a);
            y0b = __builtin_elementwise_fma(s0[2*k+1], w23, y0b);
            y1a = __builtin_elementwise_fma(s1[2*k],   w01, y1a);
            y1b = __builtin_elementwise_fma(s1[2*k+1], w23, y1b);
            y2a = __builtin_elementwise_fma(s2[2*k],   w01, y2a);
            y2b = __builtin_elementwise_fma(s2[2*k+1], w23, y2b);
            v4t q = *(const v4t*)(p3 + 4 * k);
            v2 q01 = __builtin_shufflevector(q, q, 0, 1);
            v2 q23 = __builtin_shufflevector(q, q, 2, 3);
            y3a = __builtin_elementwise_fma(q01, w01, y3a);
            y3b = __builtin_elementwise_fma(q23, w23, y3b);
        }
        float r0 = (y0a.x + y0a.y) + (y0b.x + y0b.y);
        float r1 = (y1a.x + y1a.y) + (y1b.x + y1b.y);
        float r2 = (y2a.x + y2a.y) + (y2b.x + y2b.y);
        float r3 = (y3a.x + y3a.y) + (y3b.x + y3b.y);
        r0 += dpp_zero<0x4E>(r0); r1 += dpp_zero<0x4E>(r1);
        r2 += dpp_zero<0x4E>(r2); r3 += dpp_zero<0x4E>(r3);
        r0 += dpp_zero<0xB1>(r0); r1 += dpp_zero<0xB1>(r1);
        r2 += dpp_zero<0xB1>(r2); r3 += dpp_zero<0xB1>(r3);
        float a01 = (tj & 1) ? r1 : r0;
        float a23 = (tj & 1) ? r3 : r2;
        return (tj & 2) ? a23 : a01;
    };

    // ---- power iteration: each wave's copy initialized to 1/16 (wave-local)
    {
        v4t c = {0.0625f, 0.0625f, 0.0625f, 0.0625f};
        *(v4t*)(wme + wst) = c;
    }

    float y_last = 0.f, a_last = 1.f;
#pragma unroll 1
    for (int pi = 0; pi < NPOW; ++pi) {
        float y = matvec();
        stage[pi & 1][tid] = y;
        __syncthreads();
        v4t u4 = *(const v4t*)(&stage[pi & 1][4 * lane]);
        float ss = fmaf(u4.x, u4.x, fmaf(u4.y, u4.y, fmaf(u4.z, u4.z, u4.w * u4.w)));
        float a  = 1.f / (sqrtf(rdlane63(wave_sum63(ss))) + EPSF);
        v4t n4 = {a * u4.x, a * u4.y, a * u4.z, a * u4.w};
        *(v4t*)(wme + wst) = n4;          // full normalized vector, my copy
        y_last = y; a_last = a;
    }

    // ---- lmax = v' S v ; momentum-safe step + beta
    float stepf, bmom;
    {
        float ysv = matvec();
        float p   = (a_last * y_last) * ysv;
        stage[0][tid] = p;
        __syncthreads();
        v4t p4 = *(const v4t*)(&stage[0][4 * lane]);
        float lmax = rdlane63(wave_sum63((p4.x + p4.y) + (p4.z + p4.w)));
        // L_safe: 1.15x headroom over the Rayleigh-quotient underestimate —
        // Nesterov needs step <= 1/L_true (plain PGD tolerated up to 2/L).
        float Lsafe = 1.15f * (2.f * lmax + 2.f * lam2) + 1e-6f;
        stepf = 1.f / Lsafe;
        float mu = 2.f * lam2 + 2e-3f;          // certified: sigma >= 1e-3 I
        float q  = sqrtf(mu / Lsafe);
        bmom = (1.f - q) / (1.f + q);
        __syncthreads();   // everyone done with stage[0] before PGD reuses it
    }

    // ---- PGD init: w0 = z0 = 1/256 (wave-local full copy)
    float w_own = 1.f / 256.f;     // projected iterate (output)
    float z_own = 1.f / 256.f;     // extrapolated iterate (matvec input)
    {
        v4t c = {1.f/256.f, 1.f/256.f, 1.f/256.f, 1.f/256.f};
        *(v4t*)(wme + wst) = c;
    }
    const float Ac = 1.f - 2.f * lam2 * stepf;
    const float Bc = -2.f * stepf;
    const float Cc = stepf * (bt - lam1 + 2.f * lam2 * wp);

    float tau_pred = 0.f;   // warm-start/extrapolated probe for next iter
    float tau_last = 0.f;   // tau of previous iteration
    float dtau_last = 0.f;  // previous tau delta (for Aitken)

    v4t w4_prev = {1.f/256.f, 1.f/256.f, 1.f/256.f, 1.f/256.f};
    float dm1 = 1.f, dm2 = 1.f;   // last two max|dw| (uniform across waves)

#pragma unroll 1
    for (int it = 0; it < NPGD; ++it) {
        // uniform early stop near fixed point
        if (it >= MINIT && dm1 < STOPTOL && dm2 < STOPTOL) break;
        // restart heuristic: growing updates => drop momentum this iter
        const float bm = (dm1 > 1.2f * dm2) ? 0.f : bmom;

        float y = matvec();                           // y = Sigma * z
        float v_own = fmaf(z_own, Ac, fmaf(y, Bc, Cc));
        const int sb = it & 1;
        stage[sb][tid] = v_own;
        __syncthreads();                      // the ONLY barrier this iteration

        __builtin_amdgcn_s_setprio(1);        // critical chain: win issue slots
        v4t v4 = *(const v4t*)(&stage[sb][4 * lane]);

        // ---- FAST PATH: evaluate only f(tau_pred) — a single S-chain.
        float tau = tau_pred;
        {
            float d0 = v4.x - tau, d1 = v4.y - tau;
            float d2 = v4.z - tau, d3 = v4.w - tau;
            float c0 = __builtin_amdgcn_fmed3f(d0, 0.f, MAXW);
            float c1 = __builtin_amdgcn_fmed3f(d1, 0.f, MAXW);
            float c2 = __builtin_amdgcn_fmed3f(d2, 0.f, MAXW);
            float c3 = __builtin_amdgcn_fmed3f(d3, 0.f, MAXW);
            float Sw = wave_sum63((c0 + c1) + (c2 + c3));
            float f  = rdlane63(Sw) - 1.f;

            if (!(fabsf(f) <= FTOL)) {        // uniform scalar branch
                // ---- SLOW PATH: build bracket (mn/mx) + count at tau.
                float mnl = fminf(fminf(v4.x, v4.y), fminf(v4.z, v4.w));
                float mxl = fmaxf(fmaxf(v4.x, v4.y), fmaxf(v4.z, v4.w));
                float n0 = ((d0 > 0.f) & (d0 < MAXW)) ? 1.f : 0.f;
                float n1 = ((d1 > 0.f) & (d1 < MAXW)) ? 1.f : 0.f;
                float n2 = ((d2 > 0.f) & (d2 < MAXW)) ? 1.f : 0.f;
                float n3 = ((d3 > 0.f) & (d3 < MAXW)) ? 1.f : 0.f;
                float mnw = wave_min63(mnl);
                float mxw = wave_max63(mxl);
                float Nw  = wave_sum63((n0 + n1) + (n2 + n3));
                float mn  = rdlane63(mnw);
                float mx  = rdlane63(mxw);
                float cnt = rdlane63(Nw);
                // Known bracket values: f(mn-MAXW)=256*MAXW-1, f(mx)=-1.
                bool pos0 = f > 0.f;
                float lo  = pos0 ? tau : mn - MAXW;
                float flo = pos0 ? f   : 256.f * MAXW - 1.f;
                float hi  = pos0 ? mx  : tau;
                float fhi = pos0 ? -1.f : f;
                int side  = pos0 ? 1 : -1;
#pragma unroll 1
                for (int r = 1; r < NILLMAX; ++r) {
                    // Newton (exact on current linear segment); Illinois
                    // secant fallback when out-of-bracket / cnt==0 / NaN.
                    float tn = fmaf(f, __builtin_amdgcn_rcpf(cnt), tau);
                    float ts = (lo * fhi - hi * flo) *
                               __builtin_amdgcn_rcpf(fhi - flo);
                    bool good = (tn > lo) & (tn < hi);
                    tau = good ? tn : ts;
                    float e0 = v4.x - tau, e1 = v4.y - tau;
                    float e2 = v4.z - tau, e3 = v4.w - tau;
                    float g0 = __builtin_amdgcn_fmed3f(e0, 0.f, MAXW);
                    float g1 = __builtin_amdgcn_fmed3f(e1, 0.f, MAXW);
                    float g2 = __builtin_amdgcn_fmed3f(e2, 0.f, MAXW);
                    float g3 = __builtin_amdgcn_fmed3f(e3, 0.f, MAXW);
                    float m0 = ((e0 > 0.f) & (e0 < MAXW)) ? 1.f : 0.f;
                    float m1 = ((e1 > 0.f) & (e1 < MAXW)) ? 1.f : 0.f;
                    float m2 = ((e2 > 0.f) & (e2 < MAXW)) ? 1.f : 0.f;
                    float m3 = ((e3 > 0.f) & (e3 < MAXW)) ? 1.f : 0.f;
                    float Sr = wave_sum63((g0 + g1) + (g2 + g3));
                    float Nr = wave_sum63((m0 + m1) + (m2 + m3));
                    f   = rdlane63(Sr) - 1.f;
                    cnt = rdlane63(Nr);
                    if (fabsf(f) <= FTOL) break;  // uniform
                    bool pos = f > 0.f;
                    float nflo = pos ? f   : ((side < 0) ? 0.5f * flo : flo);
                    float nfhi = pos ? ((side > 0) ? 0.5f * fhi : fhi) : f;
                    lo  = pos ? tau : lo;
                    hi  = pos ? hi  : tau;
                    flo = nflo; fhi = nfhi;
                    side = pos ? 1 : -1;
                }
            }
        }

        // ---- Aitken predictor (uniform, off critical path)
        {
            float dtau = tau - tau_last;
            float rho  = dtau * __builtin_amdgcn_rcpf(dtau_last);
            bool okx = (fabsf(dtau_last) > 1e-20f) & (rho > 0.f) &
                       (rho < 0.9f) & (fabsf(dtau) < 1e-2f);
            float extr = okx ? dtau * rho * __builtin_amdgcn_rcpf(1.f - rho) : 0.f;
            tau_pred = tau + extr;
            tau_last = tau;
            dtau_last = dtau;
        }

        // ---- project, extrapolate (Nesterov), publish z to my wave's copy
        v4t w4n = {__builtin_amdgcn_fmed3f(v4.x - tau, 0.f, MAXW),
                   __builtin_amdgcn_fmed3f(v4.y - tau, 0.f, MAXW),
                   __builtin_amdgcn_fmed3f(v4.z - tau, 0.f, MAXW),
                   __builtin_amdgcn_fmed3f(v4.w - tau, 0.f, MAXW)};
        v4t z4 = {fmaf(bm, w4n.x - w4_prev.x, w4n.x),
                  fmaf(bm, w4n.y - w4_prev.y, w4n.y),
                  fmaf(bm, w4n.z - w4_prev.z, w4n.z),
                  fmaf(bm, w4n.w - w4_prev.w, w4n.w)};
        *(v4t*)(wme + wst) = z4;
        __builtin_amdgcn_s_setprio(0);        // back to throughput phase
        float w_new = __builtin_amdgcn_fmed3f(v_own - tau, 0.f, MAXW);
        z_own = fmaf(bm, w_new - w_own, w_new);
        w_own = w_new;

        // ---- max|dw| chain, off critical path; consumed next iteration.
        {
            float pm = fmaxf(fmaxf(fabsf(w4n.x - w4_prev.x),
                                   fabsf(w4n.y - w4_prev.y)),
                             fmaxf(fabsf(w4n.z - w4_prev.z),
                                   fabsf(w4n.w - w4_prev.w)));
            w4_prev = w4n;
            dm2 = dm1;
            dm1 = rdlane63(wave_max63(pm));
        }
    }

    // ---- renormalize + store (barrier first: exit parity is data-dependent)
    __syncthreads();
    stage[0][tid] = w_own;
    __syncthreads();
    v4t w4 = *(const v4t*)(&stage[0][4 * lane]);
    float S = rdlane63(wave_sum63((w4.x + w4.y) + (w4.z + w4.w)));
    out[b * PP + tid] = w_own / (S + EPSF);
}

extern "C" void kernel_launch(void* const* d_in, const int* in_sizes, int n_in,
                              void* d_out, int out_size, void* d_ws, size_t ws_size,
                              hipStream_t stream) {
    const float* sigma  = (const float*)d_in[0];
    const float* beta   = (const float*)d_in[1];
    const float* wprevp = (const float*)d_in[2];
    const float* pl1    = (const float*)d_in[3];
    const float* pl2    = (const float*)d_in[4];
    float* outp = (float*)d_out;
    drb_kernel<<<dim3(512), dim3(256), 0, stream>>>(sigma, beta, wprevp, pl1, pl2, outp);
}

// Round 8
// 272.397 us; speedup vs baseline: 2.1619x; 1.1171x over previous
//
#include <hip/hip_runtime.h>
#include <math.h>

// DifferentiableRiskBudgeting: B=512, P=256. One block (256 thr) per batch.
// Thread (ti=tid>>2, tj=tid&3) owns rows 4ti..4ti+3 x cols 64tj..64tj+63.
//   Rows +0..2: fp32 VGPRs as <2 x float> pairs -> v_pk_fma_f32.
//   Row  +3: fp32 LDS slab, stride 272 + tj-stride 68 (conflict-free b128).
// Capacity: 2 blocks/CU fills RF+LDS; occupancy is not a lever.
// R8 (WIN -40%): warm-start Newton + early exit. R10 (WIN -5.5%): lean fast
// path. R12 (WIN -57%): 8-chain matvec ILP + rigorous early stop — absmax
// bit-identical => only the fixed point matters (strongly convex QP).
// R13 (WIN -14%): Nesterov, N_eff ~95 -> ~67. Under-delivered: tail decay
// throttled by STOPTOL=1e-7 (~12 extra iters/decade at rho~0.83), restarts
// at 1.2x firing on benign momentum oscillation, and NPOW=20 (~25us fixed)
// estimating lmax far beyond what the 1.15x headroom needs.
// R14: STOPTOL 1e-6 (cert. residual ~5e-6 << 2.44e-4), restart factor 2.0
//   (fixed-beta Nesterov is stable; only catastrophic growth zeroes beta),
//   NPOW 10 (RQ error few % inside 1.15x), MINIT 20.

#define PP    256
#define MAXW  0.1f
#define EPSF  1e-8f
#define NPGD  250
#define NPOW  10
#define NILLMAX 10
#define FTOL  4e-6f
#define STOPTOL 1e-6f
#define MINIT 20

#define R3S   272   // sigma row-3 slab stride (floats); 272 % 32 == 16
#define TJS   68    // tj stride inside slab row;        68 % 32 == 4
#define WRDS  72    // w-copy block stride (64 data + 8 stagger)
#define VCOPY 280   // per-wave w copy stride

typedef float v2 __attribute__((ext_vector_type(2)));
typedef float v4t __attribute__((ext_vector_type(4)));

template<int CTRL>
__device__ __forceinline__ float dpp_zero(float x) {
    return __int_as_float(__builtin_amdgcn_update_dpp(
        0, __float_as_int(x), CTRL, 0xF, 0xF, true));
}
template<int CTRL>
__device__ __forceinline__ float dpp_keep(float x) {
    int xi = __float_as_int(x);
    return __int_as_float(__builtin_amdgcn_update_dpp(xi, xi, CTRL, 0xF, 0xF, false));
}
__device__ __forceinline__ float rdlane63(float x) {
    return __int_as_float(__builtin_amdgcn_readlane(__float_as_int(x), 63));
}
__device__ __forceinline__ float wave_sum63(float s) {
    s += dpp_zero<0x111>(s);
    s += dpp_zero<0x112>(s);
    s += dpp_zero<0x114>(s);
    s += dpp_zero<0x118>(s);
    s += dpp_zero<0x142>(s);
    s += dpp_zero<0x143>(s);
    return s;
}
__device__ __forceinline__ float wave_min63(float m) {
    m = fminf(m, dpp_keep<0x111>(m));
    m = fminf(m, dpp_keep<0x112>(m));
    m = fminf(m, dpp_keep<0x114>(m));
    m = fminf(m, dpp_keep<0x118>(m));
    m = fminf(m, dpp_keep<0x142>(m));
    m = fminf(m, dpp_keep<0x143>(m));
    return m;
}
__device__ __forceinline__ float wave_max63(float m) {
    m = fmaxf(m, dpp_keep<0x111>(m));
    m = fmaxf(m, dpp_keep<0x112>(m));
    m = fmaxf(m, dpp_keep<0x114>(m));
    m = fmaxf(m, dpp_keep<0x118>(m));
    m = fmaxf(m, dpp_keep<0x142>(m));
    m = fmaxf(m, dpp_keep<0x143>(m));
    return m;
}

__global__ __launch_bounds__(256, 2)
__attribute__((amdgpu_waves_per_eu(2, 2)))
void drb_kernel(const float* __restrict__ sigma,
                const float* __restrict__ beta,
                const float* __restrict__ wprev,
                const float* __restrict__ pl1,
                const float* __restrict__ pl2,
                float* __restrict__ out)
{
    const int b    = blockIdx.x;
    const int tid  = threadIdx.x;
    const int lane = tid & 63;
    const int wv   = tid >> 6;
    const int ti   = tid >> 2;   // 0..63
    const int tj   = tid & 3;    // 0..3

    __shared__ __align__(16) float sigR3[64 * R3S];   // 69632 B
    __shared__ __align__(16) float wcop[4 * VCOPY];   //  4480 B
    __shared__ __align__(16) float stage[2][256];     //  2048 B

    const float* Sb = sigma + (size_t)b * (PP * PP);

    // ---- stage sigma: rows +0..2 -> v2 VGPR pairs; row +3 -> LDS slab.
    v2 s0[32], s1[32], s2[32];
    {
        const float* r0 = Sb + (4 * ti + 0) * PP + 64 * tj;
#pragma unroll
        for (int k = 0; k < 16; ++k) {
            v4t t = *(const v4t*)(r0 + 4 * k);
            s0[2*k]   = __builtin_shufflevector(t, t, 0, 1);
            s0[2*k+1] = __builtin_shufflevector(t, t, 2, 3);
        }
    }
    {
        const float* r1 = Sb + (4 * ti + 1) * PP + 64 * tj;
#pragma unroll
        for (int k = 0; k < 16; ++k) {
            v4t t = *(const v4t*)(r1 + 4 * k);
            s1[2*k]   = __builtin_shufflevector(t, t, 0, 1);
            s1[2*k+1] = __builtin_shufflevector(t, t, 2, 3);
        }
    }
    {
        const float* r2 = Sb + (4 * ti + 2) * PP + 64 * tj;
#pragma unroll
        for (int k = 0; k < 16; ++k) {
            v4t t = *(const v4t*)(r2 + 4 * k);
            s2[2*k]   = __builtin_shufflevector(t, t, 0, 1);
            s2[2*k+1] = __builtin_shufflevector(t, t, 2, 3);
        }
    }
    {
        const float* r3 = Sb + (4 * ti + 3) * PP + 64 * tj;
        float* d3 = sigR3 + ti * R3S + TJS * tj;
#pragma unroll
        for (int k = 0; k < 16; ++k)
            *(v4t*)(d3 + 4 * k) = *(const v4t*)(r3 + 4 * k);
        // row-3 slab is written and read by the SAME thread -> no barrier.
    }

    const float bt   = beta[b * PP + tid];
    const float wp   = wprev[b * PP + tid];
    const float lam1 = expf(pl1[0]);
    const float lam2 = expf(pl2[0]);

    float* wme = wcop + wv * VCOPY;                // my wave's full-vector copy
    const int wst = 4 * lane + 8 * (lane >> 4);    // staggered write slot
    const float* wrd = wme + WRDS * tj;            // matvec read base (72*tj)

    // y = Sigma * z (z from my wave's copy); returns y[row tid].
    // 8 independent accumulator chains (even/odd k).
    auto matvec = [&]() -> float {
        v2 y0a = {0.f, 0.f}, y0b = {0.f, 0.f};
        v2 y1a = {0.f, 0.f}, y1b = {0.f, 0.f};
        v2 y2a = {0.f, 0.f}, y2b = {0.f, 0.f};
        v2 y3a = {0.f, 0.f}, y3b = {0.f, 0.f};
        const float* p3 = sigR3 + ti * R3S + TJS * tj;
#pragma unroll
        for (int k = 0; k < 16; ++k) {
            v4t wq = *(const v4t*)(wrd + 4 * k);
            v2 w01 = __builtin_shufflevector(wq, wq, 0, 1);
            v2 w23 = __builtin_shufflevector(wq, wq, 2, 3);
            y0a = __builtin_elementwise_fma(s0[2*k],   w01, y0a);
            y0b = __builtin_elementwise_fma(s0[2*k+1], w23, y0b);
            y1a = __builtin_elementwise_fma(s1[2*k],   w01, y1a);
            y1b = __builtin_elementwise_fma(s1[2*k+1], w23, y1b);
            y2a = __builtin_elementwise_fma(s2[2*k],   w01, y2a);
            y2b = __builtin_elementwise_fma(s2[2*k+1], w23, y2b);
            v4t q = *(const v4t*)(p3 + 4 * k);
            v2 q01 = __builtin_shufflevector(q, q, 0, 1);
            v2 q23 = __builtin_shufflevector(q, q, 2, 3);
            y3a = __builtin_elementwise_fma(q01, w01, y3a);
            y3b = __builtin_elementwise_fma(q23, w23, y3b);
        }
        float r0 = (y0a.x + y0a.y) + (y0b.x + y0b.y);
        float r1 = (y1a.x + y1a.y) + (y1b.x + y1b.y);
        float r2 = (y2a.x + y2a.y) + (y2b.x + y2b.y);
        float r3 = (y3a.x + y3a.y) + (y3b.x + y3b.y);
        r0 += dpp_zero<0x4E>(r0); r1 += dpp_zero<0x4E>(r1);
        r2 += dpp_zero<0x4E>(r2); r3 += dpp_zero<0x4E>(r3);
        r0 += dpp_zero<0xB1>(r0); r1 += dpp_zero<0xB1>(r1);
        r2 += dpp_zero<0xB1>(r2); r3 += dpp_zero<0xB1>(r3);
        float a01 = (tj & 1) ? r1 : r0;
        float a23 = (tj & 1) ? r3 : r2;
        return (tj & 2) ? a23 : a01;
    };

    // ---- power iteration: each wave's copy initialized to 1/16 (wave-local)
    {
        v4t c = {0.0625f, 0.0625f, 0.0625f, 0.0625f};
        *(v4t*)(wme + wst) = c;
    }

    float y_last = 0.f, a_last = 1.f;
#pragma unroll 1
    for (int pi = 0; pi < NPOW; ++pi) {
        float y = matvec();
        stage[pi & 1][tid] = y;
        __syncthreads();
        v4t u4 = *(const v4t*)(&stage[pi & 1][4 * lane]);
        float ss = fmaf(u4.x, u4.x, fmaf(u4.y, u4.y, fmaf(u4.z, u4.z, u4.w * u4.w)));
        float a  = 1.f / (sqrtf(rdlane63(wave_sum63(ss))) + EPSF);
        v4t n4 = {a * u4.x, a * u4.y, a * u4.z, a * u4.w};
        *(v4t*)(wme + wst) = n4;          // full normalized vector, my copy
        y_last = y; a_last = a;
    }

    // ---- lmax = v' S v ; momentum-safe step + beta
    float stepf, bmom;
    {
        float ysv = matvec();
        float p   = (a_last * y_last) * ysv;
        stage[0][tid] = p;
        __syncthreads();
        v4t p4 = *(const v4t*)(&stage[0][4 * lane]);
        float lmax = rdlane63(wave_sum63((p4.x + p4.y) + (p4.z + p4.w)));
        // L_safe: 1.15x headroom over the Rayleigh-quotient underestimate —
        // Nesterov needs step <= 1/L_true (plain PGD tolerated up to 2/L).
        float Lsafe = 1.15f * (2.f * lmax + 2.f * lam2) + 1e-6f;
        stepf = 1.f / Lsafe;
        float mu = 2.f * lam2 + 2e-3f;          // certified: sigma >= 1e-3 I
        float q  = sqrtf(mu / Lsafe);
        bmom = (1.f - q) / (1.f + q);
        __syncthreads();   // everyone done with stage[0] before PGD reuses it
    }

    // ---- PGD init: w0 = z0 = 1/256 (wave-local full copy)
    float w_own = 1.f / 256.f;     // projected iterate (output)
    float z_own = 1.f / 256.f;     // extrapolated iterate (matvec input)
    {
        v4t c = {1.f/256.f, 1.f/256.f, 1.f/256.f, 1.f/256.f};
        *(v4t*)(wme + wst) = c;
    }
    const float Ac = 1.f - 2.f * lam2 * stepf;
    const float Bc = -2.f * stepf;
    const float Cc = stepf * (bt - lam1 + 2.f * lam2 * wp);

    float tau_pred = 0.f;   // warm-start/extrapolated probe for next iter
    float tau_last = 0.f;   // tau of previous iteration
    float dtau_last = 0.f;  // previous tau delta (for Aitken)

    v4t w4_prev = {1.f/256.f, 1.f/256.f, 1.f/256.f, 1.f/256.f};
    float dm1 = 1.f, dm2 = 1.f;   // last two max|dw| (uniform across waves)

#pragma unroll 1
    for (int it = 0; it < NPGD; ++it) {
        // uniform early stop near fixed point (residual <~ 5*STOPTOL)
        if (it >= MINIT && dm1 < STOPTOL && dm2 < STOPTOL) break;
        // restart only on catastrophic growth (benign Nesterov oscillation
        // must NOT zero beta — that was throttling R13)
        const float bm = (dm1 > 2.0f * dm2) ? 0.f : bmom;

        float y = matvec();                           // y = Sigma * z
        float v_own = fmaf(z_own, Ac, fmaf(y, Bc, Cc));
        const int sb = it & 1;
        stage[sb][tid] = v_own;
        __syncthreads();                      // the ONLY barrier this iteration

        __builtin_amdgcn_s_setprio(1);        // critical chain: win issue slots
        v4t v4 = *(const v4t*)(&stage[sb][4 * lane]);

        // ---- FAST PATH: evaluate only f(tau_pred) — a single S-chain.
        float tau = tau_pred;
        {
            float d0 = v4.x - tau, d1 = v4.y - tau;
            float d2 = v4.z - tau, d3 = v4.w - tau;
            float c0 = __builtin_amdgcn_fmed3f(d0, 0.f, MAXW);
            float c1 = __builtin_amdgcn_fmed3f(d1, 0.f, MAXW);
            float c2 = __builtin_amdgcn_fmed3f(d2, 0.f, MAXW);
            float c3 = __builtin_amdgcn_fmed3f(d3, 0.f, MAXW);
            float Sw = wave_sum63((c0 + c1) + (c2 + c3));
            float f  = rdlane63(Sw) - 1.f;

            if (!(fabsf(f) <= FTOL)) {        // uniform scalar branch
                // ---- SLOW PATH: build bracket (mn/mx) + count at tau.
                float mnl = fminf(fminf(v4.x, v4.y), fminf(v4.z, v4.w));
                float mxl = fmaxf(fmaxf(v4.x, v4.y), fmaxf(v4.z, v4.w));
                float n0 = ((d0 > 0.f) & (d0 < MAXW)) ? 1.f : 0.f;
                float n1 = ((d1 > 0.f) & (d1 < MAXW)) ? 1.f : 0.f;
                float n2 = ((d2 > 0.f) & (d2 < MAXW)) ? 1.f : 0.f;
                float n3 = ((d3 > 0.f) & (d3 < MAXW)) ? 1.f : 0.f;
                float mnw = wave_min63(mnl);
                float mxw = wave_max63(mxl);
                float Nw  = wave_sum63((n0 + n1) + (n2 + n3));
                float mn  = rdlane63(mnw);
                float mx  = rdlane63(mxw);
                float cnt = rdlane63(Nw);
                // Known bracket values: f(mn-MAXW)=256*MAXW-1, f(mx)=-1.
                bool pos0 = f > 0.f;
                float lo  = pos0 ? tau : mn - MAXW;
                float flo = pos0 ? f   : 256.f * MAXW - 1.f;
                float hi  = pos0 ? mx  : tau;
                float fhi = pos0 ? -1.f : f;
                int side  = pos0 ? 1 : -1;
#pragma unroll 1
                for (int r = 1; r < NILLMAX; ++r) {
                    // Newton (exact on current linear segment); Illinois
                    // secant fallback when out-of-bracket / cnt==0 / NaN.
                    float tn = fmaf(f, __builtin_amdgcn_rcpf(cnt), tau);
                    float ts = (lo * fhi - hi * flo) *
                               __builtin_amdgcn_rcpf(fhi - flo);
                    bool good = (tn > lo) & (tn < hi);
                    tau = good ? tn : ts;
                    float e0 = v4.x - tau, e1 = v4.y - tau;
                    float e2 = v4.z - tau, e3 = v4.w - tau;
                    float g0 = __builtin_amdgcn_fmed3f(e0, 0.f, MAXW);
                    float g1 = __builtin_amdgcn_fmed3f(e1, 0.f, MAXW);
                    float g2 = __builtin_amdgcn_fmed3f(e2, 0.f, MAXW);
                    float g3 = __builtin_amdgcn_fmed3f(e3, 0.f, MAXW);
                    float m0 = ((e0 > 0.f) & (e0 < MAXW)) ? 1.f : 0.f;
                    float m1 = ((e1 > 0.f) & (e1 < MAXW)) ? 1.f : 0.f;
                    float m2 = ((e2 > 0.f) & (e2 < MAXW)) ? 1.f : 0.f;
                    float m3 = ((e3 > 0.f) & (e3 < MAXW)) ? 1.f : 0.f;
                    float Sr = wave_sum63((g0 + g1) + (g2 + g3));
                    float Nr = wave_sum63((m0 + m1) + (m2 + m3));
                    f   = rdlane63(Sr) - 1.f;
                    cnt = rdlane63(Nr);
                    if (fabsf(f) <= FTOL) break;  // uniform
                    bool pos = f > 0.f;
                    float nflo = pos ? f   : ((side < 0) ? 0.5f * flo : flo);
                    float nfhi = pos ? ((side > 0) ? 0.5f * fhi : fhi) : f;
                    lo  = pos ? tau : lo;
                    hi  = pos ? hi  : tau;
                    flo = nflo; fhi = nfhi;
                    side = pos ? 1 : -1;
                }
            }
        }

        // ---- Aitken predictor (uniform, off critical path)
        {
            float dtau = tau - tau_last;
            float rho  = dtau * __builtin_amdgcn_rcpf(dtau_last);
            bool okx = (fabsf(dtau_last) > 1e-20f) & (rho > 0.f) &
                       (rho < 0.9f) & (fabsf(dtau) < 1e-2f);
            float extr = okx ? dtau * rho * __builtin_amdgcn_rcpf(1.f - rho) : 0.f;
            tau_pred = tau + extr;
            tau_last = tau;
            dtau_last = dtau;
        }

        // ---- project, extrapolate (Nesterov), publish z to my wave's copy
        v4t w4n = {__builtin_amdgcn_fmed3f(v4.x - tau, 0.f, MAXW),
                   __builtin_amdgcn_fmed3f(v4.y - tau, 0.f, MAXW),
                   __builtin_amdgcn_fmed3f(v4.z - tau, 0.f, MAXW),
                   __builtin_amdgcn_fmed3f(v4.w - tau, 0.f, MAXW)};
        v4t z4 = {fmaf(bm, w4n.x - w4_prev.x, w4n.x),
                  fmaf(bm, w4n.y - w4_prev.y, w4n.y),
                  fmaf(bm, w4n.z - w4_prev.z, w4n.z),
                  fmaf(bm, w4n.w - w4_prev.w, w4n.w)};
        *(v4t*)(wme + wst) = z4;
        __builtin_amdgcn_s_setprio(0);        // back to throughput phase
        float w_new = __builtin_amdgcn_fmed3f(v_own - tau, 0.f, MAXW);
        z_own = fmaf(bm, w_new - w_own, w_new);
        w_own = w_new;

        // ---- max|dw| chain, off critical path; consumed next iteration.
        {
            float pm = fmaxf(fmaxf(fabsf(w4n.x - w4_prev.x),
                                   fabsf(w4n.y - w4_prev.y)),
                             fmaxf(fabsf(w4n.z - w4_prev.z),
                                   fabsf(w4n.w - w4_prev.w)));
            w4_prev = w4n;
            dm2 = dm1;
            dm1 = rdlane63(wave_max63(pm));
        }
    }

    // ---- renormalize + store (barrier first: exit parity is data-dependent)
    __syncthreads();
    stage[0][tid] = w_own;
    __syncthreads();
    v4t w4 = *(const v4t*)(&stage[0][4 * lane]);
    float S = rdlane63(wave_sum63((w4.x + w4.y) + (w4.z + w4.w)));
    out[b * PP + tid] = w_own / (S + EPSF);
}

extern "C" void kernel_launch(void* const* d_in, const int* in_sizes, int n_in,
                              void* d_out, int out_size, void* d_ws, size_t ws_size,
                              hipStream_t stream) {
    const float* sigma  = (const float*)d_in[0];
    const float* beta   = (const float*)d_in[1];
    const float* wprevp = (const float*)d_in[2];
    const float* pl1    = (const float*)d_in[3];
    const float* pl2    = (const float*)d_in[4];
    float* outp = (float*)d_out;
    drb_kernel<<<dim3(512), dim3(256), 0, stream>>>(sigma, beta, wprevp, pl1, pl2, outp);
}